// Round 12
// baseline (172.831 us; speedup 1.0000x reference)
//
#include <hip/hip_runtime.h>
#include <cstdint>

constexpr int B  = 64;
constexpr int N  = 1723;
constexpr int E  = 1723;
constexpr int NNZ = 16384;
constexpr int ROWS = B * N;   // 110272

typedef __bf16 bf16x8 __attribute__((ext_vector_type(8)));
typedef float  f32x4  __attribute__((ext_vector_type(4)));

// ---------------- workspace layout ----------------
constexpr size_t OFF_DD   = 0;
constexpr size_t OFF_BD   = OFF_DD + E;
constexpr size_t OFF_NCUR = OFF_BD + E;
constexpr size_t OFF_ECUR = OFF_NCUR + E;
constexpr size_t OFF_NOFF = OFF_ECUR + E;
constexpr size_t OFF_EOFF = OFF_NOFF + (E + 1);
constexpr size_t OFF_NVAL = OFF_EOFF + (E + 1);
constexpr size_t OFF_EVAL = OFF_NVAL + NNZ;

// bf16 weight region element offsets (within Wb)
constexpr int WB_LIN1 = 0;            // 64*256  = 16384
constexpr int WB_TH1  = 16384;        // 32*64   -> +2048
constexpr int WB_TH2  = 18432;        // 128*32  -> +4096
constexpr int WB_LIN2 = 22528;        // 256*128 -> +32768
constexpr int WB_TOT  = 55296;
constexpr int CVT_BLOCKS  = WB_TOT / 8 / 256;         // 27
constexpr int ZERO_INTS   = 4 * E;                    // 6892
constexpr int ZERO_BLOCKS = (ZERO_INTS + 255) / 256;  // 27

constexpr size_t B_WB    = 262144;            // 110 KB of bf16 weights
constexpr size_t B_SLOTB = 4u << 20;          // xl1 / ef2 (7.06 MB)
constexpr size_t B_SLOTC = B_SLOTB + (8u << 20);   // ef1
constexpr size_t B_SLOTD = B_SLOTC + (8u << 20);   // y2

// ---------------- helpers ----------------
__device__ __forceinline__ ushort f2bf(float f) {
  uint32_t b = __float_as_uint(f);
  b += 0x7fffu + ((b >> 16) & 1u);
  return (ushort)(b >> 16);
}
__device__ __forceinline__ float bf2f(ushort u) {
  return __uint_as_float((uint32_t)u << 16);
}
union U16x8 { uint4 q; ushort s[8]; };

// ---------------- init: weights -> bf16 AND zero CSR counters ----------------
__global__ __launch_bounds__(256) void k_init(const float* __restrict__ W1, const float* __restrict__ W2,
                                              const float* __restrict__ W3, const float* __restrict__ W4,
                                              ushort* __restrict__ out, int* __restrict__ zr) {
  int bid = blockIdx.x;
  if (bid < CVT_BLOCKS) {
    int e = (bid * 256 + threadIdx.x) * 8;
    const float* src;
    int off;
    if (e < WB_TH1)      { src = W1; off = e - WB_LIN1; }
    else if (e < WB_TH2) { src = W2; off = e - WB_TH1; }
    else if (e < WB_LIN2){ src = W3; off = e - WB_TH2; }
    else                 { src = W4; off = e - WB_LIN2; }
    float4 v0 = *(const float4*)(src + off);
    float4 v1 = *(const float4*)(src + off + 4);
    U16x8 u;
    u.s[0] = f2bf(v0.x); u.s[1] = f2bf(v0.y); u.s[2] = f2bf(v0.z); u.s[3] = f2bf(v0.w);
    u.s[4] = f2bf(v1.x); u.s[5] = f2bf(v1.y); u.s[6] = f2bf(v1.z); u.s[7] = f2bf(v1.w);
    *(uint4*)(out + e) = u.q;
  } else {
    int i = (bid - CVT_BLOCKS) * 256 + threadIdx.x;
    if (i < ZERO_INTS) zr[i] = 0;
  }
}

// ---------------- CSR build (parallel, multi-kernel) ----------------
__global__ __launch_bounds__(256) void k_hist(const int* __restrict__ inc,
                                              int* __restrict__ Dd, int* __restrict__ Bd) {
  int k = blockIdx.x * 256 + threadIdx.x;
  atomicAdd(&Dd[inc[k]], 1);
  atomicAdd(&Bd[inc[NNZ + k]], 1);
}

__global__ __launch_bounds__(256) void k_scan(const int* __restrict__ Dd, const int* __restrict__ Bd,
                                              int* __restrict__ noff, int* __restrict__ eoff) {
  __shared__ int part[256];
  const int t = threadIdx.x;
  for (int pass = 0; pass < 2; ++pass) {
    const int* cnt = pass ? Bd : Dd;
    int* off = pass ? eoff : noff;
    constexpr int CH = 7;
    int loc[CH];
    int s = 0;
    int base = t * CH;
#pragma unroll
    for (int i = 0; i < CH; ++i) {
      int idx = base + i;
      loc[i] = (idx < E) ? cnt[idx] : 0;
      s += loc[i];
    }
    part[t] = s;
    __syncthreads();
    for (int d = 1; d < 256; d <<= 1) {
      int v = (t >= d) ? part[t - d] : 0;
      __syncthreads();
      part[t] += v;
      __syncthreads();
    }
    int pre = (t > 0) ? part[t - 1] : 0;
#pragma unroll
    for (int i = 0; i < CH; ++i) {
      int idx = base + i;
      if (idx < E) off[idx] = pre;
      pre += loc[i];
    }
    if (t == 255) off[E] = pre;
    __syncthreads();
  }
}

__global__ __launch_bounds__(256) void k_fill(const int* __restrict__ inc,
                                              const int* __restrict__ noff, const int* __restrict__ eoff,
                                              int* __restrict__ ncur, int* __restrict__ ecur,
                                              int* __restrict__ nval, int* __restrict__ eval) {
  int k = blockIdx.x * 256 + threadIdx.x;
  int n = inc[k], e = inc[NNZ + k];
  int p = atomicAdd(&ecur[e], 1);
  eval[eoff[e] + p] = n;
  int q = atomicAdd(&ncur[n], 1);
  nval[noff[n] + q] = e;
}

// LDS-buffered per-segment insertion sort (stride 33 -> conflict-free)
__global__ __launch_bounds__(256) void k_sort2(const int* __restrict__ noff, int* __restrict__ nval,
                                               const int* __restrict__ eoff, int* __restrict__ eval) {
  __shared__ int buf[256][33];
  int s = blockIdx.x * 256 + threadIdx.x;
  const int* off;
  int* vals;
  if (s < E) { off = noff; vals = nval; }
  else if (s < 2 * E) { off = eoff; vals = eval; s -= E; }
  else return;
  int b = off[s], e = off[s + 1], len = e - b;
  int* loc = buf[threadIdx.x];
  if (len <= 32) {
    for (int i = 0; i < len; ++i) loc[i] = vals[b + i];
    for (int i = 1; i < len; ++i) {
      int v = loc[i];
      int j = i - 1;
      while (j >= 0 && loc[j] > v) { loc[j + 1] = loc[j]; --j; }
      loc[j + 1] = v;
    }
    for (int i = 0; i < len; ++i) vals[b + i] = loc[i];
  } else {
    for (int i = b + 1; i < e; ++i) {
      int v = vals[i];
      int j = i - 1;
      while (j >= b && vals[j] > v) { vals[j + 1] = vals[j]; --j; }
      vals[j + 1] = v;
    }
  }
}

// ---------------- fused lin1 + LN + relu + th1 ----------------
__global__ __launch_bounds__(256, 3) void k_lin1th1(const float* __restrict__ x,
                                                    const ushort* __restrict__ Wb,
                                                    const float* __restrict__ lin1_b,
                                                    const float* __restrict__ pre_g,
                                                    const float* __restrict__ pre_b,
                                                    const float* __restrict__ n1_g,
                                                    const float* __restrict__ n1_b,
                                                    ushort* __restrict__ xl1) {
  __shared__ __align__(16) uint4 R0[2048];   // A1 [64][32]; later: ost f32[64][68] @0, A2 @1152
  __shared__ __align__(16) uint4 W2s[256];   // th1 [32][8]
  __shared__ float2 st[64];

  const int t = threadIdx.x;
  const int r0 = blockIdx.x * 64;
  const ushort* W1 = Wb + WB_LIN1;
  const ushort* W2 = Wb + WB_TH1;

  const int lane = t & 63;
  const int w = t >> 6;
  const int lo = lane & 15, hi = lane >> 4;
  const int wm = w & 1, wn = w >> 1;
  const int m0 = wm * 32 + lo, m1 = wm * 32 + 16 + lo;

  // lin1 W fragments -> registers (L2-resident 32KB)
  bf16x8 wf[16];
#pragma unroll
  for (int ks = 0; ks < 8; ++ks)
#pragma unroll
    for (int f = 0; f < 2; ++f) {
      int n = wn * 32 + f * 16 + lo;
      wf[ks * 2 + f] = *(const bf16x8*)(W1 + (size_t)n * 256 + (ks * 4 + hi) * 8);
    }

  {
    int row = t >> 3, c = t & 7;
    W2s[row * 8 + (c ^ (row & 7))] = *(const uint4*)(W2 + row * 64 + c * 8);
  }
#pragma unroll
  for (int i = 0; i < 8; ++i) {
    int idx = t + i * 256;
    int row = idx >> 5, c = idx & 31;
    const float* src = x + (size_t)(r0 + row) * 256 + c * 8;
    float4 v0 = *(const float4*)src;
    float4 v1 = *(const float4*)(src + 4);
    U16x8 u;
    u.s[0] = f2bf(v0.x); u.s[1] = f2bf(v0.y); u.s[2] = f2bf(v0.z); u.s[3] = f2bf(v0.w);
    u.s[4] = f2bf(v1.x); u.s[5] = f2bf(v1.y); u.s[6] = f2bf(v1.z); u.s[7] = f2bf(v1.w);
    R0[row * 32 + (c ^ (row & 7))] = u.q;
  }
  __syncthreads();

  // LN1 stats
  {
    int row = t >> 2, part = t & 3;
    float s1 = 0.f, s2 = 0.f;
#pragma unroll
    for (int i = 0; i < 8; ++i) {
      int c = part * 8 + i;
      U16x8 u; u.q = R0[row * 32 + (c ^ (row & 7))];
#pragma unroll
      for (int j = 0; j < 8; ++j) { float v = bf2f(u.s[j]); s1 += v; s2 += v * v; }
    }
    s1 += __shfl_xor(s1, 1, 64); s2 += __shfl_xor(s2, 1, 64);
    s1 += __shfl_xor(s1, 2, 64); s2 += __shfl_xor(s2, 2, 64);
    if (part == 0) {
      float mu = s1 / 256.f;
      float var = fmaxf(s2 / 256.f - mu * mu, 0.f);
      st[row] = make_float2(mu, rsqrtf(var + 1e-5f));
    }
  }
  __syncthreads();
  // apply LN1 + relu in place
#pragma unroll
  for (int i = 0; i < 8; ++i) {
    int idx = t + i * 256;
    int row = idx >> 5, c = idx & 31;
    int slot = row * 32 + (c ^ (row & 7));
    U16x8 u; u.q = R0[slot];
    float2 s = st[row];
    float4 g0 = *(const float4*)(pre_g + c * 8);
    float4 g1 = *(const float4*)(pre_g + c * 8 + 4);
    float4 b0 = *(const float4*)(pre_b + c * 8);
    float4 b1 = *(const float4*)(pre_b + c * 8 + 4);
    U16x8 o;
    o.s[0] = f2bf(fmaxf(fmaf((bf2f(u.s[0]) - s.x) * s.y, g0.x, b0.x), 0.f));
    o.s[1] = f2bf(fmaxf(fmaf((bf2f(u.s[1]) - s.x) * s.y, g0.y, b0.y), 0.f));
    o.s[2] = f2bf(fmaxf(fmaf((bf2f(u.s[2]) - s.x) * s.y, g0.z, b0.z), 0.f));
    o.s[3] = f2bf(fmaxf(fmaf((bf2f(u.s[3]) - s.x) * s.y, g0.w, b0.w), 0.f));
    o.s[4] = f2bf(fmaxf(fmaf((bf2f(u.s[4]) - s.x) * s.y, g1.x, b1.x), 0.f));
    o.s[5] = f2bf(fmaxf(fmaf((bf2f(u.s[5]) - s.x) * s.y, g1.y, b1.y), 0.f));
    o.s[6] = f2bf(fmaxf(fmaf((bf2f(u.s[6]) - s.x) * s.y, g1.z, b1.z), 0.f));
    o.s[7] = f2bf(fmaxf(fmaf((bf2f(u.s[7]) - s.x) * s.y, g1.w, b1.w), 0.f));
    R0[slot] = o.q;
  }
  __syncthreads();

  // MFMA1: K=256, NOUT=64
  const bf16x8* Asv = (const bf16x8*)R0;
  f32x4 acc1[2][2] = {};
#pragma unroll
  for (int ks = 0; ks < 8; ++ks) {
    int cb = ks * 4 + hi;
    bf16x8 a0 = Asv[m0 * 32 + (cb ^ (m0 & 7))];
    bf16x8 a1 = Asv[m1 * 32 + (cb ^ (m1 & 7))];
#pragma unroll
    for (int f = 0; f < 2; ++f) {
      acc1[0][f] = __builtin_amdgcn_mfma_f32_16x16x32_bf16(a0, wf[ks * 2 + f], acc1[0][f], 0, 0, 0);
      acc1[1][f] = __builtin_amdgcn_mfma_f32_16x16x32_bf16(a1, wf[ks * 2 + f], acc1[1][f], 0, 0, 0);
    }
  }
  __syncthreads();

  float* ost = (float*)R0;
#pragma unroll
  for (int f = 0; f < 2; ++f) {
    int colg = wn * 32 + f * 16 + lo;
    float badd = lin1_b[colg];
#pragma unroll
    for (int i = 0; i < 2; ++i)
#pragma unroll
      for (int r = 0; r < 4; ++r) {
        int lr = wm * 32 + i * 16 + hi * 4 + r;
        ost[lr * 68 + colg] = acc1[i][f][r] + badd;
      }
  }
  __syncthreads();

  // LN2 stats
  {
    int row = t >> 2, part = t & 3;
    float s1 = 0.f, s2 = 0.f;
#pragma unroll
    for (int i = 0; i < 16; ++i) {
      float v = ost[row * 68 + part * 16 + i];
      s1 += v; s2 += v * v;
    }
    s1 += __shfl_xor(s1, 1, 64); s2 += __shfl_xor(s2, 1, 64);
    s1 += __shfl_xor(s1, 2, 64); s2 += __shfl_xor(s2, 2, 64);
    if (part == 0) {
      float mu = s1 / 64.f;
      float var = fmaxf(s2 / 64.f - mu * mu, 0.f);
      st[row] = make_float2(mu, rsqrtf(var + 1e-5f));
    }
  }
  __syncthreads();
  uint4* A2q = R0 + 1152;
#pragma unroll
  for (int i = 0; i < 2; ++i) {
    int idx = t + i * 256;
    int row = idx >> 3, c = idx & 7;
    float2 s = st[row];
    U16x8 u;
#pragma unroll
    for (int j = 0; j < 8; ++j) {
      int col = c * 8 + j;
      float v = ost[row * 68 + col];
      u.s[j] = f2bf(fmaxf(fmaf((v - s.x) * s.y, n1_g[col], n1_b[col]), 0.f));
    }
    A2q[row * 8 + (c ^ (row & 7))] = u.q;
  }
  __syncthreads();

  // MFMA2: K=64, NOUT=32
  const bf16x8* A2v = (const bf16x8*)A2q;
  f32x4 acc2[2] = {};
#pragma unroll
  for (int ks = 0; ks < 2; ++ks) {
    int cb = ks * 4 + hi;
    bf16x8 a0 = A2v[m0 * 8 + (cb ^ (m0 & 7))];
    bf16x8 a1 = A2v[m1 * 8 + (cb ^ (m1 & 7))];
    int n = wn * 16 + lo;
    bf16x8 bfr = ((const bf16x8*)W2s)[n * 8 + (cb ^ (n & 7))];
    acc2[0] = __builtin_amdgcn_mfma_f32_16x16x32_bf16(a0, bfr, acc2[0], 0, 0, 0);
    acc2[1] = __builtin_amdgcn_mfma_f32_16x16x32_bf16(a1, bfr, acc2[1], 0, 0, 0);
  }
  {
    int colg = wn * 16 + lo;
#pragma unroll
    for (int i = 0; i < 2; ++i)
#pragma unroll
      for (int r = 0; r < 4; ++r) {
        int lr = wm * 32 + i * 16 + hi * 4 + r;
        ost[lr * 36 + colg] = acc2[i][r];
      }
  }
  __syncthreads();
  {
    int lr = t >> 2, c8 = t & 3;
    uint32_t r = r0 + lr;
    uint32_t b_ = r / (uint32_t)N;
    uint32_t n_ = r - b_ * (uint32_t)N;
    U16x8 u;
#pragma unroll
    for (int j = 0; j < 8; ++j) u.s[j] = f2bf(ost[lr * 36 + c8 * 8 + j]);
    *(uint4*)(xl1 + ((size_t)n_ * 64 + b_) * 32 + c8 * 8) = u.q;
  }
}

// ---------------- bf16 hypergraph aggregation, C=32, 2-deep pipelined gather ----------------
template <bool HASB>
__global__ __launch_bounds__(256) void agg_bf16_k(const ushort* __restrict__ in,
                                                  const int* __restrict__ off,
                                                  const int* __restrict__ vals,
                                                  const float* __restrict__ bias,
                                                  ushort* __restrict__ outb) {
  const int seg = blockIdx.x;
  const int beg = off[seg], end = off[seg + 1];
  const int t = threadIdx.x;
  float acc[8] = {0.f, 0.f, 0.f, 0.f, 0.f, 0.f, 0.f, 0.f};
  if (beg < end) {
    uint4 cur = *(const uint4*)(in + (size_t)vals[beg] * 2048 + t * 8);
    for (int k = beg + 1; k < end; ++k) {
      uint4 nxt = *(const uint4*)(in + (size_t)vals[k] * 2048 + t * 8);
      U16x8 u; u.q = cur;
#pragma unroll
      for (int j = 0; j < 8; ++j) acc[j] += bf2f(u.s[j]);
      cur = nxt;
    }
    U16x8 u; u.q = cur;
#pragma unroll
    for (int j = 0; j < 8; ++j) acc[j] += bf2f(u.s[j]);
  }
  float inv = (end > beg) ? 1.f / (float)(end - beg) : 0.f;
  U16x8 o;
  if constexpr (HASB) {
    int cb = (t & 3) * 8;
#pragma unroll
    for (int j = 0; j < 8; ++j) o.s[j] = f2bf(acc[j] * inv + bias[cb + j]);
  } else {
#pragma unroll
    for (int j = 0; j < 8; ++j) o.s[j] = f2bf(acc[j] * inv);
  }
  *(uint4*)(outb + (size_t)seg * 2048 + t * 8) = o.q;
}

// ---------------- fused node-agg + th2 + LN + relu + lin2 + skip ----------------
// block = node n: gather ef2 -> A(64x32) -> y3 = A@th2^T+bi2 -> y3n = relu(LN(y3)) (LDS only)
// -> out = x + y3n @ lin2_W^T + lin2_b  (64 rows x 256 cols, W staged per 128-col half)
__global__ __launch_bounds__(256, 2) void k_aggl2(const ushort* __restrict__ ef2,
                                                  const int* __restrict__ noff,
                                                  const int* __restrict__ nval,
                                                  const ushort* __restrict__ W2b,
                                                  const float* __restrict__ bi2,
                                                  const float* __restrict__ n2_g,
                                                  const float* __restrict__ n2_b,
                                                  const ushort* __restrict__ Wl2,
                                                  const float* __restrict__ lin2_b,
                                                  const float* __restrict__ x,
                                                  float* __restrict__ out) {
  __shared__ __align__(16) uint4 A2s[256];    // gather out [64][4]
  __shared__ __align__(16) uint4 W2s[512];    // th2 [128][4]
  __shared__ __align__(16) uint4 AsQ[1024];   // y3n bf16 [64][16]
  __shared__ __align__(16) char  big[34816];  // ost f32[64][132] | WsQ [128][16] | epi f32[64][68]
  __shared__ float2 st[64];
  const int t = threadIdx.x;
  const int seg = blockIdx.x;

  const int lane = t & 63;
  const int w = t >> 6;
  const int lo = lane & 15, hi = lane >> 4;
  const int wm = w & 1, wn = w >> 1;
  const int m0 = wm * 32 + lo, m1 = wm * 32 + 16 + lo;

  // stage th2
#pragma unroll
  for (int i = 0; i < 2; ++i) {
    int idx = t + i * 256;
    int row = idx >> 2, c = idx & 3;
    W2s[row * 4 + (c ^ (row & 3))] = *(const uint4*)(W2b + row * 32 + c * 8);
  }
  // gather (2-deep pipelined)
  const int beg = noff[seg], end = noff[seg + 1];
  float acc[8] = {0.f, 0.f, 0.f, 0.f, 0.f, 0.f, 0.f, 0.f};
  if (beg < end) {
    uint4 cur = *(const uint4*)(ef2 + (size_t)nval[beg] * 2048 + t * 8);
    for (int k = beg + 1; k < end; ++k) {
      uint4 nxt = *(const uint4*)(ef2 + (size_t)nval[k] * 2048 + t * 8);
      U16x8 u; u.q = cur;
#pragma unroll
      for (int j = 0; j < 8; ++j) acc[j] += bf2f(u.s[j]);
      cur = nxt;
    }
    U16x8 u; u.q = cur;
#pragma unroll
    for (int j = 0; j < 8; ++j) acc[j] += bf2f(u.s[j]);
  }
  float inv = (end > beg) ? 1.f / (float)(end - beg) : 0.f;
  {
    U16x8 u;
#pragma unroll
    for (int j = 0; j < 8; ++j) u.s[j] = f2bf(acc[j] * inv);
    int row = t >> 2, c = t & 3;
    A2s[row * 4 + (c ^ (row & 3))] = u.q;
  }
  __syncthreads();

  // th2 MFMA: K=32, NOUT=128 -> ost + bi2
  float* ost = (float*)big;
  {
    const bf16x8* Asv = (const bf16x8*)A2s;
    const bf16x8* Wsv = (const bf16x8*)W2s;
    f32x4 acc2[2][4] = {};
    bf16x8 a0 = Asv[m0 * 4 + (hi ^ (m0 & 3))];
    bf16x8 a1 = Asv[m1 * 4 + (hi ^ (m1 & 3))];
#pragma unroll
    for (int f = 0; f < 4; ++f) {
      int n = wn * 64 + f * 16 + lo;
      bf16x8 bfr = Wsv[n * 4 + (hi ^ (n & 3))];
      acc2[0][f] = __builtin_amdgcn_mfma_f32_16x16x32_bf16(a0, bfr, acc2[0][f], 0, 0, 0);
      acc2[1][f] = __builtin_amdgcn_mfma_f32_16x16x32_bf16(a1, bfr, acc2[1][f], 0, 0, 0);
    }
#pragma unroll
    for (int f = 0; f < 4; ++f) {
      int colg = wn * 64 + f * 16 + lo;
      float badd = bi2[colg];
#pragma unroll
      for (int i = 0; i < 2; ++i)
#pragma unroll
        for (int r = 0; r < 4; ++r) {
          int lr = wm * 32 + i * 16 + hi * 4 + r;
          ost[lr * 132 + colg] = acc2[i][f][r] + badd;
        }
    }
  }
  __syncthreads();
  // LN stats over 128
  {
    int row = t >> 2, part = t & 3;
    float s1 = 0.f, s2 = 0.f;
#pragma unroll
    for (int i = 0; i < 32; ++i) {
      float v = ost[row * 132 + part * 32 + i];
      s1 += v; s2 += v * v;
    }
    s1 += __shfl_xor(s1, 1, 64); s2 += __shfl_xor(s2, 1, 64);
    s1 += __shfl_xor(s1, 2, 64); s2 += __shfl_xor(s2, 2, 64);
    if (part == 0) {
      float mu = s1 / 128.f;
      float var = fmaxf(s2 / 128.f - mu * mu, 0.f);
      st[row] = make_float2(mu, rsqrtf(var + 1e-5f));
    }
  }
  __syncthreads();
  // apply LN + relu -> y3n bf16 into AsQ [64][16] (XOR swizzle, same layout as lin2 A)
#pragma unroll
  for (int i = 0; i < 4; ++i) {
    int idx = t + i * 256;
    int row = idx >> 4, c = idx & 15;
    float2 s = st[row];
    U16x8 u;
#pragma unroll
    for (int j = 0; j < 8; ++j) {
      int col = c * 8 + j;
      float v = ost[row * 132 + col];
      u.s[j] = f2bf(fmaxf(fmaf((v - s.x) * s.y, n2_g[col], n2_b[col]), 0.f));
    }
    AsQ[row * 16 + (c ^ (row & 7))] = u.q;
  }
  __syncthreads();   // ost dead; AsQ visible

  // lin2: two 128-col halves; W half staged into big (overwrites ost)
  const bf16x8* Asv = (const bf16x8*)AsQ;
  uint4* WsQ = (uint4*)big;
#pragma unroll
  for (int half = 0; half < 2; ++half) {
    // stage W half: rows [half*128, half*128+128) x 128 cols -> [128][16] uint4
#pragma unroll
    for (int i = 0; i < 8; ++i) {
      int idx = t + i * 256;
      int row = idx >> 4, c = idx & 15;
      WsQ[row * 16 + (c ^ (row & 7))] = *(const uint4*)(Wl2 + (size_t)(half * 128 + row) * 128 + c * 8);
    }
    __syncthreads();
    const bf16x8* Wsv = (const bf16x8*)WsQ;
    f32x4 accl[2][4] = {};
#pragma unroll
    for (int ks = 0; ks < 4; ++ks) {
      int cb = ks * 4 + hi;
      bf16x8 a0 = Asv[m0 * 16 + (cb ^ (m0 & 7))];
      bf16x8 a1 = Asv[m1 * 16 + (cb ^ (m1 & 7))];
#pragma unroll
      for (int f = 0; f < 4; ++f) {
        int n = wn * 64 + f * 16 + lo;
        bf16x8 bfr = Wsv[n * 16 + (cb ^ (n & 7))];
        accl[0][f] = __builtin_amdgcn_mfma_f32_16x16x32_bf16(a0, bfr, accl[0][f], 0, 0, 0);
        accl[1][f] = __builtin_amdgcn_mfma_f32_16x16x32_bf16(a1, bfr, accl[1][f], 0, 0, 0);
      }
    }
    __syncthreads();   // WsQ dead
    // chunked epilogue: 2 x 64-col chunks; chunk == wn of owning waves
    float* epi = (float*)big;
#pragma unroll
    for (int chunk = 0; chunk < 2; ++chunk) {
      if (wn == chunk) {
#pragma unroll
        for (int f = 0; f < 4; ++f) {
          int cl = f * 16 + lo;
          float badd = lin2_b[half * 128 + chunk * 64 + cl];
#pragma unroll
          for (int i = 0; i < 2; ++i)
#pragma unroll
            for (int r = 0; r < 4; ++r) {
              int lr = wm * 32 + i * 16 + hi * 4 + r;
              epi[lr * 68 + cl] = accl[i][f][r] + badd;
            }
        }
      }
      __syncthreads();
      // coalesced skip+write of 64 rows x 64 cols
#pragma unroll
      for (int i = 0; i < 4; ++i) {
        int idx = t + i * 256;
        int lr = idx >> 4, c4 = idx & 15;
        size_t obase = ((size_t)lr * N + seg) * 256 + half * 128 + chunk * 64 + c4 * 4;
        float4 v = *(const float4*)&epi[lr * 68 + c4 * 4];
        float4 s = *(const float4*)(x + obase);
        v.x += s.x; v.y += s.y; v.z += s.z; v.w += s.w;
        *(float4*)(out + obase) = v;
      }
      __syncthreads();
    }
  }
}

// ---------------- launch ----------------
extern "C" void kernel_launch(void* const* d_in, const int* in_sizes, int n_in,
                              void* d_out, int out_size, void* d_ws, size_t ws_size,
                              hipStream_t stream) {
  const float* x      = (const float*)d_in[0];
  const int*   inc    = (const int*)  d_in[1];
  const float* pre_g  = (const float*)d_in[2];
  const float* pre_b  = (const float*)d_in[3];
  const float* lin1_W = (const float*)d_in[4];
  const float* lin1_b = (const float*)d_in[5];
  const float* n1_g   = (const float*)d_in[6];
  const float* n1_b   = (const float*)d_in[7];
  const float* th1    = (const float*)d_in[8];
  const float* bi1    = (const float*)d_in[9];
  const float* th2    = (const float*)d_in[10];
  const float* bi2    = (const float*)d_in[11];
  const float* n2_g   = (const float*)d_in[12];
  const float* n2_b   = (const float*)d_in[13];
  const float* lin2_W = (const float*)d_in[14];
  const float* lin2_b = (const float*)d_in[15];
  float* out = (float*)d_out;
  char* ws = (char*)d_ws;

  int* meta = (int*)ws;
  int* Dd   = meta + OFF_DD;
  int* Bd   = meta + OFF_BD;
  int* ncur = meta + OFF_NCUR;
  int* ecur = meta + OFF_ECUR;
  int* noff = meta + OFF_NOFF;
  int* eoff = meta + OFF_EOFF;
  int* nval = meta + OFF_NVAL;
  int* eval = meta + OFF_EVAL;

  ushort* Wbase = (ushort*)(ws + B_WB);
  ushort* xl1 = (ushort*)(ws + B_SLOTB);   // (ROWS,32) bf16 node-major
  ushort* ef2 = (ushort*)(ws + B_SLOTB);   // reuse after xl1 dead
  ushort* ef1 = (ushort*)(ws + B_SLOTC);
  ushort* y2  = (ushort*)(ws + B_SLOTD);

  k_init<<<CVT_BLOCKS + ZERO_BLOCKS, 256, 0, stream>>>(lin1_W, th1, th2, lin2_W, Wbase, meta);
  k_hist<<<NNZ / 256, 256, 0, stream>>>(inc, Dd, Bd);
  k_scan<<<1, 256, 0, stream>>>(Dd, Bd, noff, eoff);
  k_fill<<<NNZ / 256, 256, 0, stream>>>(inc, noff, eoff, ncur, ecur, nval, eval);
  k_sort2<<<(2 * E + 255) / 256, 256, 0, stream>>>(noff, nval, eoff, eval);

  // xl1 = th1(relu(LN(lin1(relu(LN(x))))))
  k_lin1th1<<<ROWS / 64, 256, 0, stream>>>(x, Wbase, lin1_b, pre_g, pre_b, n1_g, n1_b, xl1);

  // propagation (C=32, bf16): hconv1 then hconv2 (theta commutes with P)
  agg_bf16_k<false><<<E, 256, 0, stream>>>(xl1, eoff, eval, nullptr, ef1);
  agg_bf16_k<true ><<<E, 256, 0, stream>>>(ef1, noff, nval, bi1, y2);
  agg_bf16_k<false><<<E, 256, 0, stream>>>(y2, eoff, eval, nullptr, ef2);

  // out = x + lin2(relu(LN(node_agg(ef2) @ th2^T + bi2)))
  k_aggl2<<<E, 256, 0, stream>>>(ef2, noff, nval, Wbase + WB_TH2, bi2, n2_g, n2_b,
                                 Wbase + WB_LIN2, lin2_b, x, out);
}

// Round 13
// 167.849 us; speedup vs baseline: 1.0297x; 1.0297x over previous
//
#include <hip/hip_runtime.h>
#include <cstdint>

constexpr int B  = 64;
constexpr int N  = 1723;
constexpr int E  = 1723;
constexpr int NNZ = 16384;
constexpr int ROWS = B * N;   // 110272

typedef __bf16 bf16x8 __attribute__((ext_vector_type(8)));
typedef float  f32x4  __attribute__((ext_vector_type(4)));

// ---------------- workspace layout ----------------
constexpr size_t OFF_DD   = 0;
constexpr size_t OFF_BD   = OFF_DD + E;
constexpr size_t OFF_NCUR = OFF_BD + E;
constexpr size_t OFF_ECUR = OFF_NCUR + E;
constexpr size_t OFF_NOFF = OFF_ECUR + E;
constexpr size_t OFF_EOFF = OFF_NOFF + (E + 1);
constexpr size_t OFF_NVAL = OFF_EOFF + (E + 1);
constexpr size_t OFF_EVAL = OFF_NVAL + NNZ;

// bf16 weight region element offsets (within Wb)
constexpr int WB_LIN1 = 0;            // 64*256  = 16384
constexpr int WB_TH1  = 16384;        // 32*64   -> +2048
constexpr int WB_TH2  = 18432;        // 128*32  -> +4096
constexpr int WB_LIN2 = 22528;        // 256*128 -> +32768
constexpr int WB_TOT  = 55296;
constexpr int CVT_BLOCKS  = WB_TOT / 8 / 256;         // 27
constexpr int ZERO_INTS   = 4 * E;                    // 6892
constexpr int ZERO_BLOCKS = (ZERO_INTS + 255) / 256;  // 27

constexpr size_t B_WB    = 262144;            // 110 KB of bf16 weights
constexpr size_t B_SLOTA = 1u << 20;          // y3n bf16 (ROWS,128) = 28.2 MB
constexpr size_t B_SLOTB = B_SLOTA + (30u << 20);  // xl1 / ef2 (7.06 MB)
constexpr size_t B_SLOTC = B_SLOTB + (8u << 20);   // ef1
constexpr size_t B_SLOTD = B_SLOTC + (8u << 20);   // y2

// ---------------- helpers ----------------
__device__ __forceinline__ ushort f2bf(float f) {
  uint32_t b = __float_as_uint(f);
  b += 0x7fffu + ((b >> 16) & 1u);
  return (ushort)(b >> 16);
}
__device__ __forceinline__ float bf2f(ushort u) {
  return __uint_as_float((uint32_t)u << 16);
}
union U16x8 { uint4 q; ushort s[8]; };

// ---------------- init: weights -> bf16 AND zero CSR counters ----------------
__global__ __launch_bounds__(256) void k_init(const float* __restrict__ W1, const float* __restrict__ W2,
                                              const float* __restrict__ W3, const float* __restrict__ W4,
                                              ushort* __restrict__ out, int* __restrict__ zr) {
  int bid = blockIdx.x;
  if (bid < CVT_BLOCKS) {
    int e = (bid * 256 + threadIdx.x) * 8;
    const float* src;
    int off;
    if (e < WB_TH1)      { src = W1; off = e - WB_LIN1; }
    else if (e < WB_TH2) { src = W2; off = e - WB_TH1; }
    else if (e < WB_LIN2){ src = W3; off = e - WB_TH2; }
    else                 { src = W4; off = e - WB_LIN2; }
    float4 v0 = *(const float4*)(src + off);
    float4 v1 = *(const float4*)(src + off + 4);
    U16x8 u;
    u.s[0] = f2bf(v0.x); u.s[1] = f2bf(v0.y); u.s[2] = f2bf(v0.z); u.s[3] = f2bf(v0.w);
    u.s[4] = f2bf(v1.x); u.s[5] = f2bf(v1.y); u.s[6] = f2bf(v1.z); u.s[7] = f2bf(v1.w);
    *(uint4*)(out + e) = u.q;
  } else {
    int i = (bid - CVT_BLOCKS) * 256 + threadIdx.x;
    if (i < ZERO_INTS) zr[i] = 0;
  }
}

// ---------------- CSR build (parallel, multi-kernel) ----------------
__global__ __launch_bounds__(256) void k_hist(const int* __restrict__ inc,
                                              int* __restrict__ Dd, int* __restrict__ Bd) {
  int k = blockIdx.x * 256 + threadIdx.x;
  atomicAdd(&Dd[inc[k]], 1);
  atomicAdd(&Bd[inc[NNZ + k]], 1);
}

__global__ __launch_bounds__(256) void k_scan(const int* __restrict__ Dd, const int* __restrict__ Bd,
                                              int* __restrict__ noff, int* __restrict__ eoff) {
  __shared__ int part[256];
  const int t = threadIdx.x;
  for (int pass = 0; pass < 2; ++pass) {
    const int* cnt = pass ? Bd : Dd;
    int* off = pass ? eoff : noff;
    constexpr int CH = 7;
    int loc[CH];
    int s = 0;
    int base = t * CH;
#pragma unroll
    for (int i = 0; i < CH; ++i) {
      int idx = base + i;
      loc[i] = (idx < E) ? cnt[idx] : 0;
      s += loc[i];
    }
    part[t] = s;
    __syncthreads();
    for (int d = 1; d < 256; d <<= 1) {
      int v = (t >= d) ? part[t - d] : 0;
      __syncthreads();
      part[t] += v;
      __syncthreads();
    }
    int pre = (t > 0) ? part[t - 1] : 0;
#pragma unroll
    for (int i = 0; i < CH; ++i) {
      int idx = base + i;
      if (idx < E) off[idx] = pre;
      pre += loc[i];
    }
    if (t == 255) off[E] = pre;
    __syncthreads();
  }
}

__global__ __launch_bounds__(256) void k_fill(const int* __restrict__ inc,
                                              const int* __restrict__ noff, const int* __restrict__ eoff,
                                              int* __restrict__ ncur, int* __restrict__ ecur,
                                              int* __restrict__ nval, int* __restrict__ eval) {
  int k = blockIdx.x * 256 + threadIdx.x;
  int n = inc[k], e = inc[NNZ + k];
  int p = atomicAdd(&ecur[e], 1);
  eval[eoff[e] + p] = n;
  int q = atomicAdd(&ncur[n], 1);
  nval[noff[n] + q] = e;
}

// LDS-buffered per-segment insertion sort (stride 33 -> conflict-free)
__global__ __launch_bounds__(256) void k_sort2(const int* __restrict__ noff, int* __restrict__ nval,
                                               const int* __restrict__ eoff, int* __restrict__ eval) {
  __shared__ int buf[256][33];
  int s = blockIdx.x * 256 + threadIdx.x;
  const int* off;
  int* vals;
  if (s < E) { off = noff; vals = nval; }
  else if (s < 2 * E) { off = eoff; vals = eval; s -= E; }
  else return;
  int b = off[s], e = off[s + 1], len = e - b;
  int* loc = buf[threadIdx.x];
  if (len <= 32) {
    for (int i = 0; i < len; ++i) loc[i] = vals[b + i];
    for (int i = 1; i < len; ++i) {
      int v = loc[i];
      int j = i - 1;
      while (j >= 0 && loc[j] > v) { loc[j + 1] = loc[j]; --j; }
      loc[j + 1] = v;
    }
    for (int i = 0; i < len; ++i) vals[b + i] = loc[i];
  } else {
    for (int i = b + 1; i < e; ++i) {
      int v = vals[i];
      int j = i - 1;
      while (j >= b && vals[j] > v) { vals[j + 1] = vals[j]; --j; }
      vals[j + 1] = v;
    }
  }
}

// ---------------- fused lin1 + LN + relu + th1 ----------------
__global__ __launch_bounds__(256, 3) void k_lin1th1(const float* __restrict__ x,
                                                    const ushort* __restrict__ Wb,
                                                    const float* __restrict__ lin1_b,
                                                    const float* __restrict__ pre_g,
                                                    const float* __restrict__ pre_b,
                                                    const float* __restrict__ n1_g,
                                                    const float* __restrict__ n1_b,
                                                    ushort* __restrict__ xl1) {
  __shared__ __align__(16) uint4 R0[2048];   // A1 [64][32]; later: ost f32[64][68] @0, A2 @1152
  __shared__ __align__(16) uint4 W2s[256];   // th1 [32][8]
  __shared__ float2 st[64];

  const int t = threadIdx.x;
  const int r0 = blockIdx.x * 64;
  const ushort* W1 = Wb + WB_LIN1;
  const ushort* W2 = Wb + WB_TH1;

  const int lane = t & 63;
  const int w = t >> 6;
  const int lo = lane & 15, hi = lane >> 4;
  const int wm = w & 1, wn = w >> 1;
  const int m0 = wm * 32 + lo, m1 = wm * 32 + 16 + lo;

  // lin1 W fragments -> registers (L2-resident 32KB)
  bf16x8 wf[16];
#pragma unroll
  for (int ks = 0; ks < 8; ++ks)
#pragma unroll
    for (int f = 0; f < 2; ++f) {
      int n = wn * 32 + f * 16 + lo;
      wf[ks * 2 + f] = *(const bf16x8*)(W1 + (size_t)n * 256 + (ks * 4 + hi) * 8);
    }

  {
    int row = t >> 3, c = t & 7;
    W2s[row * 8 + (c ^ (row & 7))] = *(const uint4*)(W2 + row * 64 + c * 8);
  }
#pragma unroll
  for (int i = 0; i < 8; ++i) {
    int idx = t + i * 256;
    int row = idx >> 5, c = idx & 31;
    const float* src = x + (size_t)(r0 + row) * 256 + c * 8;
    float4 v0 = *(const float4*)src;
    float4 v1 = *(const float4*)(src + 4);
    U16x8 u;
    u.s[0] = f2bf(v0.x); u.s[1] = f2bf(v0.y); u.s[2] = f2bf(v0.z); u.s[3] = f2bf(v0.w);
    u.s[4] = f2bf(v1.x); u.s[5] = f2bf(v1.y); u.s[6] = f2bf(v1.z); u.s[7] = f2bf(v1.w);
    R0[row * 32 + (c ^ (row & 7))] = u.q;
  }
  __syncthreads();

  // LN1 stats
  {
    int row = t >> 2, part = t & 3;
    float s1 = 0.f, s2 = 0.f;
#pragma unroll
    for (int i = 0; i < 8; ++i) {
      int c = part * 8 + i;
      U16x8 u; u.q = R0[row * 32 + (c ^ (row & 7))];
#pragma unroll
      for (int j = 0; j < 8; ++j) { float v = bf2f(u.s[j]); s1 += v; s2 += v * v; }
    }
    s1 += __shfl_xor(s1, 1, 64); s2 += __shfl_xor(s2, 1, 64);
    s1 += __shfl_xor(s1, 2, 64); s2 += __shfl_xor(s2, 2, 64);
    if (part == 0) {
      float mu = s1 / 256.f;
      float var = fmaxf(s2 / 256.f - mu * mu, 0.f);
      st[row] = make_float2(mu, rsqrtf(var + 1e-5f));
    }
  }
  __syncthreads();
  // apply LN1 + relu in place
#pragma unroll
  for (int i = 0; i < 8; ++i) {
    int idx = t + i * 256;
    int row = idx >> 5, c = idx & 31;
    int slot = row * 32 + (c ^ (row & 7));
    U16x8 u; u.q = R0[slot];
    float2 s = st[row];
    float4 g0 = *(const float4*)(pre_g + c * 8);
    float4 g1 = *(const float4*)(pre_g + c * 8 + 4);
    float4 b0 = *(const float4*)(pre_b + c * 8);
    float4 b1 = *(const float4*)(pre_b + c * 8 + 4);
    U16x8 o;
    o.s[0] = f2bf(fmaxf(fmaf((bf2f(u.s[0]) - s.x) * s.y, g0.x, b0.x), 0.f));
    o.s[1] = f2bf(fmaxf(fmaf((bf2f(u.s[1]) - s.x) * s.y, g0.y, b0.y), 0.f));
    o.s[2] = f2bf(fmaxf(fmaf((bf2f(u.s[2]) - s.x) * s.y, g0.z, b0.z), 0.f));
    o.s[3] = f2bf(fmaxf(fmaf((bf2f(u.s[3]) - s.x) * s.y, g0.w, b0.w), 0.f));
    o.s[4] = f2bf(fmaxf(fmaf((bf2f(u.s[4]) - s.x) * s.y, g1.x, b1.x), 0.f));
    o.s[5] = f2bf(fmaxf(fmaf((bf2f(u.s[5]) - s.x) * s.y, g1.y, b1.y), 0.f));
    o.s[6] = f2bf(fmaxf(fmaf((bf2f(u.s[6]) - s.x) * s.y, g1.z, b1.z), 0.f));
    o.s[7] = f2bf(fmaxf(fmaf((bf2f(u.s[7]) - s.x) * s.y, g1.w, b1.w), 0.f));
    R0[slot] = o.q;
  }
  __syncthreads();

  // MFMA1: K=256, NOUT=64; B-frags from registers
  const bf16x8* Asv = (const bf16x8*)R0;
  f32x4 acc1[2][2] = {};
#pragma unroll
  for (int ks = 0; ks < 8; ++ks) {
    int cb = ks * 4 + hi;
    bf16x8 a0 = Asv[m0 * 32 + (cb ^ (m0 & 7))];
    bf16x8 a1 = Asv[m1 * 32 + (cb ^ (m1 & 7))];
#pragma unroll
    for (int f = 0; f < 2; ++f) {
      acc1[0][f] = __builtin_amdgcn_mfma_f32_16x16x32_bf16(a0, wf[ks * 2 + f], acc1[0][f], 0, 0, 0);
      acc1[1][f] = __builtin_amdgcn_mfma_f32_16x16x32_bf16(a1, wf[ks * 2 + f], acc1[1][f], 0, 0, 0);
    }
  }
  __syncthreads();

  float* ost = (float*)R0;
#pragma unroll
  for (int f = 0; f < 2; ++f) {
    int colg = wn * 32 + f * 16 + lo;
    float badd = lin1_b[colg];
#pragma unroll
    for (int i = 0; i < 2; ++i)
#pragma unroll
      for (int r = 0; r < 4; ++r) {
        int lr = wm * 32 + i * 16 + hi * 4 + r;
        ost[lr * 68 + colg] = acc1[i][f][r] + badd;
      }
  }
  __syncthreads();

  // LN2 stats
  {
    int row = t >> 2, part = t & 3;
    float s1 = 0.f, s2 = 0.f;
#pragma unroll
    for (int i = 0; i < 16; ++i) {
      float v = ost[row * 68 + part * 16 + i];
      s1 += v; s2 += v * v;
    }
    s1 += __shfl_xor(s1, 1, 64); s2 += __shfl_xor(s2, 1, 64);
    s1 += __shfl_xor(s1, 2, 64); s2 += __shfl_xor(s2, 2, 64);
    if (part == 0) {
      float mu = s1 / 64.f;
      float var = fmaxf(s2 / 64.f - mu * mu, 0.f);
      st[row] = make_float2(mu, rsqrtf(var + 1e-5f));
    }
  }
  __syncthreads();
  uint4* A2q = R0 + 1152;
#pragma unroll
  for (int i = 0; i < 2; ++i) {
    int idx = t + i * 256;
    int row = idx >> 3, c = idx & 7;
    float2 s = st[row];
    U16x8 u;
#pragma unroll
    for (int j = 0; j < 8; ++j) {
      int col = c * 8 + j;
      float v = ost[row * 68 + col];
      u.s[j] = f2bf(fmaxf(fmaf((v - s.x) * s.y, n1_g[col], n1_b[col]), 0.f));
    }
    A2q[row * 8 + (c ^ (row & 7))] = u.q;
  }
  __syncthreads();

  // MFMA2: K=64, NOUT=32
  const bf16x8* A2v = (const bf16x8*)A2q;
  f32x4 acc2[2] = {};
#pragma unroll
  for (int ks = 0; ks < 2; ++ks) {
    int cb = ks * 4 + hi;
    bf16x8 a0 = A2v[m0 * 8 + (cb ^ (m0 & 7))];
    bf16x8 a1 = A2v[m1 * 8 + (cb ^ (m1 & 7))];
    int n = wn * 16 + lo;
    bf16x8 bfr = ((const bf16x8*)W2s)[n * 8 + (cb ^ (n & 7))];
    acc2[0] = __builtin_amdgcn_mfma_f32_16x16x32_bf16(a0, bfr, acc2[0], 0, 0, 0);
    acc2[1] = __builtin_amdgcn_mfma_f32_16x16x32_bf16(a1, bfr, acc2[1], 0, 0, 0);
  }
  {
    int colg = wn * 16 + lo;
#pragma unroll
    for (int i = 0; i < 2; ++i)
#pragma unroll
      for (int r = 0; r < 4; ++r) {
        int lr = wm * 32 + i * 16 + hi * 4 + r;
        ost[lr * 36 + colg] = acc2[i][r];
      }
  }
  __syncthreads();
  {
    int lr = t >> 2, c8 = t & 3;
    uint32_t r = r0 + lr;
    uint32_t b_ = r / (uint32_t)N;
    uint32_t n_ = r - b_ * (uint32_t)N;
    U16x8 u;
#pragma unroll
    for (int j = 0; j < 8; ++j) u.s[j] = f2bf(ost[lr * 36 + c8 * 8 + j]);
    *(uint4*)(xl1 + ((size_t)n_ * 64 + b_) * 32 + c8 * 8) = u.q;
  }
}

// ---------------- bf16 hypergraph aggregation, C=32, 2-deep pipelined gather ----------------
template <bool HASB>
__global__ __launch_bounds__(256) void agg_bf16_k(const ushort* __restrict__ in,
                                                  const int* __restrict__ off,
                                                  const int* __restrict__ vals,
                                                  const float* __restrict__ bias,
                                                  ushort* __restrict__ outb) {
  const int seg = blockIdx.x;
  const int beg = off[seg], end = off[seg + 1];
  const int t = threadIdx.x;
  float acc[8] = {0.f, 0.f, 0.f, 0.f, 0.f, 0.f, 0.f, 0.f};
  if (beg < end) {
    uint4 cur = *(const uint4*)(in + (size_t)vals[beg] * 2048 + t * 8);
    for (int k = beg + 1; k < end; ++k) {
      uint4 nxt = *(const uint4*)(in + (size_t)vals[k] * 2048 + t * 8);
      U16x8 u; u.q = cur;
#pragma unroll
      for (int j = 0; j < 8; ++j) acc[j] += bf2f(u.s[j]);
      cur = nxt;
    }
    U16x8 u; u.q = cur;
#pragma unroll
    for (int j = 0; j < 8; ++j) acc[j] += bf2f(u.s[j]);
  }
  float inv = (end > beg) ? 1.f / (float)(end - beg) : 0.f;
  U16x8 o;
  if constexpr (HASB) {
    int cb = (t & 3) * 8;
#pragma unroll
    for (int j = 0; j < 8; ++j) o.s[j] = f2bf(acc[j] * inv + bias[cb + j]);
  } else {
#pragma unroll
    for (int j = 0; j < 8; ++j) o.s[j] = f2bf(acc[j] * inv);
  }
  *(uint4*)(outb + (size_t)seg * 2048 + t * 8) = o.q;
}

// ---------------- fused node-agg + th2 + bi2 + LN + relu ----------------
__global__ __launch_bounds__(256, 3) void k_aggth2(const ushort* __restrict__ ef2,
                                                   const int* __restrict__ noff,
                                                   const int* __restrict__ nval,
                                                   const ushort* __restrict__ W2b,
                                                   const float* __restrict__ bi2,
                                                   const float* __restrict__ n2_g,
                                                   const float* __restrict__ n2_b,
                                                   ushort* __restrict__ y3n) {
  __shared__ __align__(16) uint4 A2s[256];   // [64][4]
  __shared__ __align__(16) uint4 W2s[512];   // [128][4]
  __shared__ float ost[64 * 132];            // 33792 B
  __shared__ float2 st[64];
  const int t = threadIdx.x;
  const int seg = blockIdx.x;

#pragma unroll
  for (int i = 0; i < 2; ++i) {
    int idx = t + i * 256;
    int row = idx >> 2, c = idx & 3;
    W2s[row * 4 + (c ^ (row & 3))] = *(const uint4*)(W2b + row * 32 + c * 8);
  }
  // gather (2-deep pipelined)
  const int beg = noff[seg], end = noff[seg + 1];
  float acc[8] = {0.f, 0.f, 0.f, 0.f, 0.f, 0.f, 0.f, 0.f};
  if (beg < end) {
    uint4 cur = *(const uint4*)(ef2 + (size_t)nval[beg] * 2048 + t * 8);
    for (int k = beg + 1; k < end; ++k) {
      uint4 nxt = *(const uint4*)(ef2 + (size_t)nval[k] * 2048 + t * 8);
      U16x8 u; u.q = cur;
#pragma unroll
      for (int j = 0; j < 8; ++j) acc[j] += bf2f(u.s[j]);
      cur = nxt;
    }
    U16x8 u; u.q = cur;
#pragma unroll
    for (int j = 0; j < 8; ++j) acc[j] += bf2f(u.s[j]);
  }
  float inv = (end > beg) ? 1.f / (float)(end - beg) : 0.f;
  {
    U16x8 u;
#pragma unroll
    for (int j = 0; j < 8; ++j) u.s[j] = f2bf(acc[j] * inv);
    int row = t >> 2, c = t & 3;
    A2s[row * 4 + (c ^ (row & 3))] = u.q;
  }
  __syncthreads();

  // MFMA: K=32 (1 step), NOUT=128
  const int lane = t & 63;
  const int w = t >> 6;
  const int lo = lane & 15, hi = lane >> 4;
  const int wm = w & 1, wn = w >> 1;
  const int m0 = wm * 32 + lo, m1 = wm * 32 + 16 + lo;
  const bf16x8* Asv = (const bf16x8*)A2s;
  const bf16x8* Wsv = (const bf16x8*)W2s;
  f32x4 acc2[2][4] = {};
  {
    bf16x8 a0 = Asv[m0 * 4 + (hi ^ (m0 & 3))];
    bf16x8 a1 = Asv[m1 * 4 + (hi ^ (m1 & 3))];
#pragma unroll
    for (int f = 0; f < 4; ++f) {
      int n = wn * 64 + f * 16 + lo;
      bf16x8 bfr = Wsv[n * 4 + (hi ^ (n & 3))];
      acc2[0][f] = __builtin_amdgcn_mfma_f32_16x16x32_bf16(a0, bfr, acc2[0][f], 0, 0, 0);
      acc2[1][f] = __builtin_amdgcn_mfma_f32_16x16x32_bf16(a1, bfr, acc2[1][f], 0, 0, 0);
    }
  }
#pragma unroll
  for (int f = 0; f < 4; ++f) {
    int colg = wn * 64 + f * 16 + lo;
    float badd = bi2[colg];
#pragma unroll
    for (int i = 0; i < 2; ++i)
#pragma unroll
      for (int r = 0; r < 4; ++r) {
        int lr = wm * 32 + i * 16 + hi * 4 + r;
        ost[lr * 132 + colg] = acc2[i][f][r] + badd;
      }
  }
  __syncthreads();
  // LN stats over 128
  {
    int row = t >> 2, part = t & 3;
    float s1 = 0.f, s2 = 0.f;
#pragma unroll
    for (int i = 0; i < 32; ++i) {
      float v = ost[row * 132 + part * 32 + i];
      s1 += v; s2 += v * v;
    }
    s1 += __shfl_xor(s1, 1, 64); s2 += __shfl_xor(s2, 1, 64);
    s1 += __shfl_xor(s1, 2, 64); s2 += __shfl_xor(s2, 2, 64);
    if (part == 0) {
      float mu = s1 / 128.f;
      float var = fmaxf(s2 / 128.f - mu * mu, 0.f);
      st[row] = make_float2(mu, rsqrtf(var + 1e-5f));
    }
  }
  __syncthreads();
#pragma unroll
  for (int i = 0; i < 4; ++i) {
    int idx = t + i * 256;
    int row = idx >> 4, c = idx & 15;
    float2 s = st[row];
    U16x8 u;
#pragma unroll
    for (int j = 0; j < 8; ++j) {
      int col = c * 8 + j;
      float v = ost[row * 132 + col];
      u.s[j] = f2bf(fmaxf(fmaf((v - s.x) * s.y, n2_g[col], n2_b[col]), 0.f));
    }
    *(uint4*)(y3n + ((size_t)seg * 64 + row) * 128 + c * 8) = u.q;
  }
}

// ---------------- lin2: col-tiled, W in LDS, skip-add, XCD-swizzled ----------------
constexpr int NWG2 = (ROWS / 64) * 4;   // 6892
__global__ __launch_bounds__(256, 4) void k_lin2(const ushort* __restrict__ y3n,
                                                 const ushort* __restrict__ Wl2,
                                                 const float* __restrict__ lin2_b,
                                                 const float* __restrict__ x,
                                                 float* __restrict__ out) {
  __shared__ __align__(16) uint4 smem[2048];  // A [64][16] + W [64][16]; ost overlay [64][68] f32
  const int t = threadIdx.x;
  // bijective XCD swizzle (m204)
  int orig = blockIdx.x;
  int xcd = orig & 7;
  int idx0 = orig >> 3;
  constexpr int q = NWG2 / 8, r = NWG2 % 8;   // 861, 4
  int wgid = (xcd < r ? xcd * (q + 1) : r * (q + 1) + (xcd - r) * q) + idx0;
  const int tile = wgid & 3;
  const int r0 = (wgid >> 2) * 64;
  const int c0 = tile * 64;
  uint4* AsQ = smem;
  uint4* WsQ = smem + 1024;

#pragma unroll
  for (int i = 0; i < 4; ++i) {
    int idx = t + i * 256;
    int row = idx >> 4, c = idx & 15;
    AsQ[row * 16 + (c ^ (row & 7))] = *(const uint4*)(y3n + (size_t)(r0 + row) * 128 + c * 8);
  }
#pragma unroll
  for (int i = 0; i < 4; ++i) {
    int idx = t + i * 256;
    int row = idx >> 4, c = idx & 15;
    WsQ[row * 16 + (c ^ (row & 7))] = *(const uint4*)(Wl2 + (size_t)(c0 + row) * 128 + c * 8);
  }
  __syncthreads();

  const int lane = t & 63;
  const int w = t >> 6;
  const int lo = lane & 15, hi = lane >> 4;
  const int wm = w & 1, wn = w >> 1;
  const int m0 = wm * 32 + lo, m1 = wm * 32 + 16 + lo;
  const bf16x8* Asv = (const bf16x8*)AsQ;
  const bf16x8* Wsv = (const bf16x8*)WsQ;
  f32x4 acc[2][2] = {};
#pragma unroll
  for (int ks = 0; ks < 4; ++ks) {
    int cb = ks * 4 + hi;
    bf16x8 a0 = Asv[m0 * 16 + (cb ^ (m0 & 7))];
    bf16x8 a1 = Asv[m1 * 16 + (cb ^ (m1 & 7))];
#pragma unroll
    for (int f = 0; f < 2; ++f) {
      int n = wn * 32 + f * 16 + lo;
      bf16x8 bfr = Wsv[n * 16 + (cb ^ (n & 7))];
      acc[0][f] = __builtin_amdgcn_mfma_f32_16x16x32_bf16(a0, bfr, acc[0][f], 0, 0, 0);
      acc[1][f] = __builtin_amdgcn_mfma_f32_16x16x32_bf16(a1, bfr, acc[1][f], 0, 0, 0);
    }
  }
  __syncthreads();

  float* ost = (float*)smem;  // [64][68]
#pragma unroll
  for (int f = 0; f < 2; ++f) {
    int cl = wn * 32 + f * 16 + lo;
    float badd = lin2_b[c0 + cl];
#pragma unroll
    for (int i = 0; i < 2; ++i)
#pragma unroll
      for (int r2 = 0; r2 < 4; ++r2) {
        int lr = wm * 32 + i * 16 + hi * 4 + r2;
        ost[lr * 68 + cl] = acc[i][f][r2] + badd;
      }
  }
  __syncthreads();

#pragma unroll
  for (int i = 0; i < 4; ++i) {
    int idx = t + i * 256;
    int lr = idx >> 4, c4 = idx & 15;
    uint32_t rr = r0 + lr;
    uint32_t n_ = rr >> 6, b_ = rr & 63u;
    size_t obase = ((size_t)b_ * N + n_) * 256 + c0 + c4 * 4;
    float4 v = *(const float4*)&ost[lr * 68 + c4 * 4];
    float4 s = *(const float4*)(x + obase);
    v.x += s.x; v.y += s.y; v.z += s.z; v.w += s.w;
    *(float4*)(out + obase) = v;
  }
}

// ---------------- launch ----------------
extern "C" void kernel_launch(void* const* d_in, const int* in_sizes, int n_in,
                              void* d_out, int out_size, void* d_ws, size_t ws_size,
                              hipStream_t stream) {
  const float* x      = (const float*)d_in[0];
  const int*   inc    = (const int*)  d_in[1];
  const float* pre_g  = (const float*)d_in[2];
  const float* pre_b  = (const float*)d_in[3];
  const float* lin1_W = (const float*)d_in[4];
  const float* lin1_b = (const float*)d_in[5];
  const float* n1_g   = (const float*)d_in[6];
  const float* n1_b   = (const float*)d_in[7];
  const float* th1    = (const float*)d_in[8];
  const float* bi1    = (const float*)d_in[9];
  const float* th2    = (const float*)d_in[10];
  const float* bi2    = (const float*)d_in[11];
  const float* n2_g   = (const float*)d_in[12];
  const float* n2_b   = (const float*)d_in[13];
  const float* lin2_W = (const float*)d_in[14];
  const float* lin2_b = (const float*)d_in[15];
  float* out = (float*)d_out;
  char* ws = (char*)d_ws;

  int* meta = (int*)ws;
  int* Dd   = meta + OFF_DD;
  int* Bd   = meta + OFF_BD;
  int* ncur = meta + OFF_NCUR;
  int* ecur = meta + OFF_ECUR;
  int* noff = meta + OFF_NOFF;
  int* eoff = meta + OFF_EOFF;
  int* nval = meta + OFF_NVAL;
  int* eval = meta + OFF_EVAL;

  ushort* Wbase = (ushort*)(ws + B_WB);
  ushort* y3n = (ushort*)(ws + B_SLOTA);   // (ROWS,128) bf16 node-major
  ushort* xl1 = (ushort*)(ws + B_SLOTB);   // (ROWS,32) bf16 node-major
  ushort* ef2 = (ushort*)(ws + B_SLOTB);   // reuse after xl1 dead
  ushort* ef1 = (ushort*)(ws + B_SLOTC);
  ushort* y2  = (ushort*)(ws + B_SLOTD);

  k_init<<<CVT_BLOCKS + ZERO_BLOCKS, 256, 0, stream>>>(lin1_W, th1, th2, lin2_W, Wbase, meta);
  k_hist<<<NNZ / 256, 256, 0, stream>>>(inc, Dd, Bd);
  k_scan<<<1, 256, 0, stream>>>(Dd, Bd, noff, eoff);
  k_fill<<<NNZ / 256, 256, 0, stream>>>(inc, noff, eoff, ncur, ecur, nval, eval);
  k_sort2<<<(2 * E + 255) / 256, 256, 0, stream>>>(noff, nval, eoff, eval);

  // xl1 = th1(relu(LN(lin1(relu(LN(x))))))
  k_lin1th1<<<ROWS / 64, 256, 0, stream>>>(x, Wbase, lin1_b, pre_g, pre_b, n1_g, n1_b, xl1);

  // propagation (C=32, bf16): hconv1 then hconv2 (theta commutes with P)
  agg_bf16_k<false><<<E, 256, 0, stream>>>(xl1, eoff, eval, nullptr, ef1);
  agg_bf16_k<true ><<<E, 256, 0, stream>>>(ef1, noff, nval, bi1, y2);
  agg_bf16_k<false><<<E, 256, 0, stream>>>(y2, eoff, eval, nullptr, ef2);

  // y3n = relu(LN(node_agg(ef2) @ th2^T + bi2))
  k_aggth2<<<E, 256, 0, stream>>>(ef2, noff, nval, Wbase + WB_TH2, bi2, n2_g, n2_b, y3n);

  // out = x + lin2(y3n)
  k_lin2<<<NWG2, 256, 0, stream>>>(y3n, Wbase + WB_LIN2, lin2_b, x, out);
}

// Round 14
// 159.846 us; speedup vs baseline: 1.0812x; 1.0501x over previous
//
#include <hip/hip_runtime.h>
#include <cstdint>

constexpr int B  = 64;
constexpr int N  = 1723;
constexpr int E  = 1723;
constexpr int NNZ = 16384;
constexpr int ROWS = B * N;   // 110272
constexpr int CAP = 64;       // fixed per-segment bucket capacity (max degree ~30 whp)

typedef __bf16 bf16x8 __attribute__((ext_vector_type(8)));
typedef float  f32x4  __attribute__((ext_vector_type(4)));

// ---------------- workspace layout (int elements from ws base) ----------------
constexpr size_t OFF_CNTN = 0;                    // int[E]
constexpr size_t OFF_CNTE = OFF_CNTN + E;         // int[E]
constexpr size_t OFF_NVAL = OFF_CNTE + E;         // int[E*CAP]
constexpr size_t OFF_EVAL = OFF_NVAL + (size_t)E * CAP;

// bf16 weight region element offsets (within Wb)
constexpr int WB_LIN1 = 0;            // 64*256  = 16384
constexpr int WB_TH1  = 16384;        // 32*64   -> +2048
constexpr int WB_TH2  = 18432;        // 128*32  -> +4096
constexpr int WB_LIN2 = 22528;        // 256*128 -> +32768
constexpr int WB_TOT  = 55296;
constexpr int CVT_BLOCKS  = WB_TOT / 8 / 256;         // 27
constexpr int ZERO_INTS   = 2 * E;                    // 3446
constexpr int ZERO_BLOCKS = (ZERO_INTS + 255) / 256;  // 14

constexpr size_t B_WB    = 1u << 20;          // bf16 weights (110 KB), past int region (~900KB)
constexpr size_t B_SLOTA = 2u << 20;          // y3n bf16 (ROWS,128) = 28.2 MB
constexpr size_t B_SLOTB = B_SLOTA + (30u << 20);  // xl1 / ef2 (7.06 MB)
constexpr size_t B_SLOTC = B_SLOTB + (8u << 20);   // ef1
constexpr size_t B_SLOTD = B_SLOTC + (8u << 20);   // y2

// ---------------- helpers ----------------
__device__ __forceinline__ ushort f2bf(float f) {
  uint32_t b = __float_as_uint(f);
  b += 0x7fffu + ((b >> 16) & 1u);
  return (ushort)(b >> 16);
}
__device__ __forceinline__ float bf2f(ushort u) {
  return __uint_as_float((uint32_t)u << 16);
}
union U16x8 { uint4 q; ushort s[8]; };

// ---------------- init: weights -> bf16 AND zero bucket counters ----------------
__global__ __launch_bounds__(256) void k_init(const float* __restrict__ W1, const float* __restrict__ W2,
                                              const float* __restrict__ W3, const float* __restrict__ W4,
                                              ushort* __restrict__ out, int* __restrict__ zr) {
  int bid = blockIdx.x;
  if (bid < CVT_BLOCKS) {
    int e = (bid * 256 + threadIdx.x) * 8;
    const float* src;
    int off;
    if (e < WB_TH1)      { src = W1; off = e - WB_LIN1; }
    else if (e < WB_TH2) { src = W2; off = e - WB_TH1; }
    else if (e < WB_LIN2){ src = W3; off = e - WB_TH2; }
    else                 { src = W4; off = e - WB_LIN2; }
    float4 v0 = *(const float4*)(src + off);
    float4 v1 = *(const float4*)(src + off + 4);
    U16x8 u;
    u.s[0] = f2bf(v0.x); u.s[1] = f2bf(v0.y); u.s[2] = f2bf(v0.z); u.s[3] = f2bf(v0.w);
    u.s[4] = f2bf(v1.x); u.s[5] = f2bf(v1.y); u.s[6] = f2bf(v1.z); u.s[7] = f2bf(v1.w);
    *(uint4*)(out + e) = u.q;
  } else {
    int i = (bid - CVT_BLOCKS) * 256 + threadIdx.x;
    if (i < ZERO_INTS) zr[i] = 0;
  }
}

// ---------------- bucket fill: fixed stride CAP, no offsets needed ----------------
__global__ __launch_bounds__(256) void k_bucket(const int* __restrict__ inc,
                                                int* __restrict__ cntN, int* __restrict__ cntE,
                                                int* __restrict__ nval, int* __restrict__ eval) {
  int k = blockIdx.x * 256 + threadIdx.x;   // grid exact: NNZ/256
  int n = inc[k], e = inc[NNZ + k];
  int p = atomicAdd(&cntE[e], 1);
  if (p < CAP) eval[e * CAP + p] = n;
  int q = atomicAdd(&cntN[n], 1);
  if (q < CAP) nval[n * CAP + q] = e;
}

// per-segment insertion sort in LDS scratch (stride 33 -> conflict-free); deterministic order
__global__ __launch_bounds__(256) void k_sort(const int* __restrict__ cntN, int* __restrict__ nval,
                                              const int* __restrict__ cntE, int* __restrict__ eval) {
  __shared__ int buf[256][33];
  int s = blockIdx.x * 256 + threadIdx.x;
  const int* cnt;
  int* vals;
  if (s < E) { cnt = cntN; vals = nval; }
  else if (s < 2 * E) { cnt = cntE; vals = eval; s -= E; }
  else return;
  int len = cnt[s];
  if (len > CAP) len = CAP;
  int base = s * CAP;
  int* loc = buf[threadIdx.x];
  if (len <= 32) {
    for (int i = 0; i < len; ++i) loc[i] = vals[base + i];
    for (int i = 1; i < len; ++i) {
      int v = loc[i];
      int j = i - 1;
      while (j >= 0 && loc[j] > v) { loc[j + 1] = loc[j]; --j; }
      loc[j + 1] = v;
    }
    for (int i = 0; i < len; ++i) vals[base + i] = loc[i];
  } else {
    for (int i = 1; i < len; ++i) {
      int v = vals[base + i];
      int j = i - 1;
      while (j >= 0 && vals[base + j] > v) { vals[base + j + 1] = vals[base + j]; --j; }
      vals[base + j + 1] = v;
    }
  }
}

// ---------------- fused lin1 + LN + relu + th1 ----------------
__global__ __launch_bounds__(256, 3) void k_lin1th1(const float* __restrict__ x,
                                                    const ushort* __restrict__ Wb,
                                                    const float* __restrict__ lin1_b,
                                                    const float* __restrict__ pre_g,
                                                    const float* __restrict__ pre_b,
                                                    const float* __restrict__ n1_g,
                                                    const float* __restrict__ n1_b,
                                                    ushort* __restrict__ xl1) {
  __shared__ __align__(16) uint4 R0[2048];   // A1 [64][32]; later: ost f32[64][68] @0, A2 @1152
  __shared__ __align__(16) uint4 W2s[256];   // th1 [32][8]
  __shared__ float2 st[64];

  const int t = threadIdx.x;
  const int r0 = blockIdx.x * 64;
  const ushort* W1 = Wb + WB_LIN1;
  const ushort* W2 = Wb + WB_TH1;

  const int lane = t & 63;
  const int w = t >> 6;
  const int lo = lane & 15, hi = lane >> 4;
  const int wm = w & 1, wn = w >> 1;
  const int m0 = wm * 32 + lo, m1 = wm * 32 + 16 + lo;

  // lin1 W fragments -> registers (L2-resident 32KB)
  bf16x8 wf[16];
#pragma unroll
  for (int ks = 0; ks < 8; ++ks)
#pragma unroll
    for (int f = 0; f < 2; ++f) {
      int n = wn * 32 + f * 16 + lo;
      wf[ks * 2 + f] = *(const bf16x8*)(W1 + (size_t)n * 256 + (ks * 4 + hi) * 8);
    }

  {
    int row = t >> 3, c = t & 7;
    W2s[row * 8 + (c ^ (row & 7))] = *(const uint4*)(W2 + row * 64 + c * 8);
  }
#pragma unroll
  for (int i = 0; i < 8; ++i) {
    int idx = t + i * 256;
    int row = idx >> 5, c = idx & 31;
    const float* src = x + (size_t)(r0 + row) * 256 + c * 8;
    float4 v0 = *(const float4*)src;
    float4 v1 = *(const float4*)(src + 4);
    U16x8 u;
    u.s[0] = f2bf(v0.x); u.s[1] = f2bf(v0.y); u.s[2] = f2bf(v0.z); u.s[3] = f2bf(v0.w);
    u.s[4] = f2bf(v1.x); u.s[5] = f2bf(v1.y); u.s[6] = f2bf(v1.z); u.s[7] = f2bf(v1.w);
    R0[row * 32 + (c ^ (row & 7))] = u.q;
  }
  __syncthreads();

  // LN1 stats
  {
    int row = t >> 2, part = t & 3;
    float s1 = 0.f, s2 = 0.f;
#pragma unroll
    for (int i = 0; i < 8; ++i) {
      int c = part * 8 + i;
      U16x8 u; u.q = R0[row * 32 + (c ^ (row & 7))];
#pragma unroll
      for (int j = 0; j < 8; ++j) { float v = bf2f(u.s[j]); s1 += v; s2 += v * v; }
    }
    s1 += __shfl_xor(s1, 1, 64); s2 += __shfl_xor(s2, 1, 64);
    s1 += __shfl_xor(s1, 2, 64); s2 += __shfl_xor(s2, 2, 64);
    if (part == 0) {
      float mu = s1 / 256.f;
      float var = fmaxf(s2 / 256.f - mu * mu, 0.f);
      st[row] = make_float2(mu, rsqrtf(var + 1e-5f));
    }
  }
  __syncthreads();
  // apply LN1 + relu in place
#pragma unroll
  for (int i = 0; i < 8; ++i) {
    int idx = t + i * 256;
    int row = idx >> 5, c = idx & 31;
    int slot = row * 32 + (c ^ (row & 7));
    U16x8 u; u.q = R0[slot];
    float2 s = st[row];
    float4 g0 = *(const float4*)(pre_g + c * 8);
    float4 g1 = *(const float4*)(pre_g + c * 8 + 4);
    float4 b0 = *(const float4*)(pre_b + c * 8);
    float4 b1 = *(const float4*)(pre_b + c * 8 + 4);
    U16x8 o;
    o.s[0] = f2bf(fmaxf(fmaf((bf2f(u.s[0]) - s.x) * s.y, g0.x, b0.x), 0.f));
    o.s[1] = f2bf(fmaxf(fmaf((bf2f(u.s[1]) - s.x) * s.y, g0.y, b0.y), 0.f));
    o.s[2] = f2bf(fmaxf(fmaf((bf2f(u.s[2]) - s.x) * s.y, g0.z, b0.z), 0.f));
    o.s[3] = f2bf(fmaxf(fmaf((bf2f(u.s[3]) - s.x) * s.y, g0.w, b0.w), 0.f));
    o.s[4] = f2bf(fmaxf(fmaf((bf2f(u.s[4]) - s.x) * s.y, g1.x, b1.x), 0.f));
    o.s[5] = f2bf(fmaxf(fmaf((bf2f(u.s[5]) - s.x) * s.y, g1.y, b1.y), 0.f));
    o.s[6] = f2bf(fmaxf(fmaf((bf2f(u.s[6]) - s.x) * s.y, g1.z, b1.z), 0.f));
    o.s[7] = f2bf(fmaxf(fmaf((bf2f(u.s[7]) - s.x) * s.y, g1.w, b1.w), 0.f));
    R0[slot] = o.q;
  }
  __syncthreads();

  // MFMA1: K=256, NOUT=64; B-frags from registers
  const bf16x8* Asv = (const bf16x8*)R0;
  f32x4 acc1[2][2] = {};
#pragma unroll
  for (int ks = 0; ks < 8; ++ks) {
    int cb = ks * 4 + hi;
    bf16x8 a0 = Asv[m0 * 32 + (cb ^ (m0 & 7))];
    bf16x8 a1 = Asv[m1 * 32 + (cb ^ (m1 & 7))];
#pragma unroll
    for (int f = 0; f < 2; ++f) {
      acc1[0][f] = __builtin_amdgcn_mfma_f32_16x16x32_bf16(a0, wf[ks * 2 + f], acc1[0][f], 0, 0, 0);
      acc1[1][f] = __builtin_amdgcn_mfma_f32_16x16x32_bf16(a1, wf[ks * 2 + f], acc1[1][f], 0, 0, 0);
    }
  }
  __syncthreads();

  float* ost = (float*)R0;
#pragma unroll
  for (int f = 0; f < 2; ++f) {
    int colg = wn * 32 + f * 16 + lo;
    float badd = lin1_b[colg];
#pragma unroll
    for (int i = 0; i < 2; ++i)
#pragma unroll
      for (int r = 0; r < 4; ++r) {
        int lr = wm * 32 + i * 16 + hi * 4 + r;
        ost[lr * 68 + colg] = acc1[i][f][r] + badd;
      }
  }
  __syncthreads();

  // LN2 stats
  {
    int row = t >> 2, part = t & 3;
    float s1 = 0.f, s2 = 0.f;
#pragma unroll
    for (int i = 0; i < 16; ++i) {
      float v = ost[row * 68 + part * 16 + i];
      s1 += v; s2 += v * v;
    }
    s1 += __shfl_xor(s1, 1, 64); s2 += __shfl_xor(s2, 1, 64);
    s1 += __shfl_xor(s1, 2, 64); s2 += __shfl_xor(s2, 2, 64);
    if (part == 0) {
      float mu = s1 / 64.f;
      float var = fmaxf(s2 / 64.f - mu * mu, 0.f);
      st[row] = make_float2(mu, rsqrtf(var + 1e-5f));
    }
  }
  __syncthreads();
  uint4* A2q = R0 + 1152;
#pragma unroll
  for (int i = 0; i < 2; ++i) {
    int idx = t + i * 256;
    int row = idx >> 3, c = idx & 7;
    float2 s = st[row];
    U16x8 u;
#pragma unroll
    for (int j = 0; j < 8; ++j) {
      int col = c * 8 + j;
      float v = ost[row * 68 + col];
      u.s[j] = f2bf(fmaxf(fmaf((v - s.x) * s.y, n1_g[col], n1_b[col]), 0.f));
    }
    A2q[row * 8 + (c ^ (row & 7))] = u.q;
  }
  __syncthreads();

  // MFMA2: K=64, NOUT=32
  const bf16x8* A2v = (const bf16x8*)A2q;
  f32x4 acc2[2] = {};
#pragma unroll
  for (int ks = 0; ks < 2; ++ks) {
    int cb = ks * 4 + hi;
    bf16x8 a0 = A2v[m0 * 8 + (cb ^ (m0 & 7))];
    bf16x8 a1 = A2v[m1 * 8 + (cb ^ (m1 & 7))];
    int n = wn * 16 + lo;
    bf16x8 bfr = ((const bf16x8*)W2s)[n * 8 + (cb ^ (n & 7))];
    acc2[0] = __builtin_amdgcn_mfma_f32_16x16x32_bf16(a0, bfr, acc2[0], 0, 0, 0);
    acc2[1] = __builtin_amdgcn_mfma_f32_16x16x32_bf16(a1, bfr, acc2[1], 0, 0, 0);
  }
  {
    int colg = wn * 16 + lo;
#pragma unroll
    for (int i = 0; i < 2; ++i)
#pragma unroll
      for (int r = 0; r < 4; ++r) {
        int lr = wm * 32 + i * 16 + hi * 4 + r;
        ost[lr * 36 + colg] = acc2[i][r];
      }
  }
  __syncthreads();
  {
    int lr = t >> 2, c8 = t & 3;
    uint32_t r = r0 + lr;
    uint32_t b_ = r / (uint32_t)N;
    uint32_t n_ = r - b_ * (uint32_t)N;
    U16x8 u;
#pragma unroll
    for (int j = 0; j < 8; ++j) u.s[j] = f2bf(ost[lr * 36 + c8 * 8 + j]);
    *(uint4*)(xl1 + ((size_t)n_ * 64 + b_) * 32 + c8 * 8) = u.q;
  }
}

// ---------------- bf16 hypergraph aggregation, C=32, bucket CSR, 2-deep pipelined ------------
template <bool HASB>
__global__ __launch_bounds__(256) void agg_bf16_k(const ushort* __restrict__ in,
                                                  const int* __restrict__ cnt,
                                                  const int* __restrict__ vals,
                                                  const float* __restrict__ bias,
                                                  ushort* __restrict__ outb) {
  const int seg = blockIdx.x;
  int len = cnt[seg];
  if (len > CAP) len = CAP;
  const int* v = vals + seg * CAP;
  const int t = threadIdx.x;
  float acc[8] = {0.f, 0.f, 0.f, 0.f, 0.f, 0.f, 0.f, 0.f};
  if (len > 0) {
    uint4 cur = *(const uint4*)(in + (size_t)v[0] * 2048 + t * 8);
    for (int k = 1; k < len; ++k) {
      uint4 nxt = *(const uint4*)(in + (size_t)v[k] * 2048 + t * 8);
      U16x8 u; u.q = cur;
#pragma unroll
      for (int j = 0; j < 8; ++j) acc[j] += bf2f(u.s[j]);
      cur = nxt;
    }
    U16x8 u; u.q = cur;
#pragma unroll
    for (int j = 0; j < 8; ++j) acc[j] += bf2f(u.s[j]);
  }
  float inv = (len > 0) ? 1.f / (float)len : 0.f;
  U16x8 o;
  if constexpr (HASB) {
    int cb = (t & 3) * 8;
#pragma unroll
    for (int j = 0; j < 8; ++j) o.s[j] = f2bf(acc[j] * inv + bias[cb + j]);
  } else {
#pragma unroll
    for (int j = 0; j < 8; ++j) o.s[j] = f2bf(acc[j] * inv);
  }
  *(uint4*)(outb + (size_t)seg * 2048 + t * 8) = o.q;
}

// ---------------- fused node-agg + th2 + bi2 + LN + relu ----------------
__global__ __launch_bounds__(256, 3) void k_aggth2(const ushort* __restrict__ ef2,
                                                   const int* __restrict__ cntN,
                                                   const int* __restrict__ nval,
                                                   const ushort* __restrict__ W2b,
                                                   const float* __restrict__ bi2,
                                                   const float* __restrict__ n2_g,
                                                   const float* __restrict__ n2_b,
                                                   ushort* __restrict__ y3n) {
  __shared__ __align__(16) uint4 A2s[256];   // [64][4]
  __shared__ __align__(16) uint4 W2s[512];   // [128][4]
  __shared__ float ost[64 * 132];
  __shared__ float2 st[64];
  const int t = threadIdx.x;
  const int seg = blockIdx.x;

#pragma unroll
  for (int i = 0; i < 2; ++i) {
    int idx = t + i * 256;
    int row = idx >> 2, c = idx & 3;
    W2s[row * 4 + (c ^ (row & 3))] = *(const uint4*)(W2b + row * 32 + c * 8);
  }
  // gather (bucket CSR, 2-deep pipelined)
  int len = cntN[seg];
  if (len > CAP) len = CAP;
  const int* v = nval + seg * CAP;
  float acc[8] = {0.f, 0.f, 0.f, 0.f, 0.f, 0.f, 0.f, 0.f};
  if (len > 0) {
    uint4 cur = *(const uint4*)(ef2 + (size_t)v[0] * 2048 + t * 8);
    for (int k = 1; k < len; ++k) {
      uint4 nxt = *(const uint4*)(ef2 + (size_t)v[k] * 2048 + t * 8);
      U16x8 u; u.q = cur;
#pragma unroll
      for (int j = 0; j < 8; ++j) acc[j] += bf2f(u.s[j]);
      cur = nxt;
    }
    U16x8 u; u.q = cur;
#pragma unroll
    for (int j = 0; j < 8; ++j) acc[j] += bf2f(u.s[j]);
  }
  float inv = (len > 0) ? 1.f / (float)len : 0.f;
  {
    U16x8 u;
#pragma unroll
    for (int j = 0; j < 8; ++j) u.s[j] = f2bf(acc[j] * inv);
    int row = t >> 2, c = t & 3;
    A2s[row * 4 + (c ^ (row & 3))] = u.q;
  }
  __syncthreads();

  // MFMA: K=32 (1 step), NOUT=128
  const int lane = t & 63;
  const int w = t >> 6;
  const int lo = lane & 15, hi = lane >> 4;
  const int wm = w & 1, wn = w >> 1;
  const int m0 = wm * 32 + lo, m1 = wm * 32 + 16 + lo;
  const bf16x8* Asv = (const bf16x8*)A2s;
  const bf16x8* Wsv = (const bf16x8*)W2s;
  f32x4 acc2[2][4] = {};
  {
    bf16x8 a0 = Asv[m0 * 4 + (hi ^ (m0 & 3))];
    bf16x8 a1 = Asv[m1 * 4 + (hi ^ (m1 & 3))];
#pragma unroll
    for (int f = 0; f < 4; ++f) {
      int n = wn * 64 + f * 16 + lo;
      bf16x8 bfr = Wsv[n * 4 + (hi ^ (n & 3))];
      acc2[0][f] = __builtin_amdgcn_mfma_f32_16x16x32_bf16(a0, bfr, acc2[0][f], 0, 0, 0);
      acc2[1][f] = __builtin_amdgcn_mfma_f32_16x16x32_bf16(a1, bfr, acc2[1][f], 0, 0, 0);
    }
  }
#pragma unroll
  for (int f = 0; f < 4; ++f) {
    int colg = wn * 64 + f * 16 + lo;
    float badd = bi2[colg];
#pragma unroll
    for (int i = 0; i < 2; ++i)
#pragma unroll
      for (int r = 0; r < 4; ++r) {
        int lr = wm * 32 + i * 16 + hi * 4 + r;
        ost[lr * 132 + colg] = acc2[i][f][r] + badd;
      }
  }
  __syncthreads();
  // LN stats over 128
  {
    int row = t >> 2, part = t & 3;
    float s1 = 0.f, s2 = 0.f;
#pragma unroll
    for (int i = 0; i < 32; ++i) {
      float v2 = ost[row * 132 + part * 32 + i];
      s1 += v2; s2 += v2 * v2;
    }
    s1 += __shfl_xor(s1, 1, 64); s2 += __shfl_xor(s2, 1, 64);
    s1 += __shfl_xor(s1, 2, 64); s2 += __shfl_xor(s2, 2, 64);
    if (part == 0) {
      float mu = s1 / 128.f;
      float var = fmaxf(s2 / 128.f - mu * mu, 0.f);
      st[row] = make_float2(mu, rsqrtf(var + 1e-5f));
    }
  }
  __syncthreads();
#pragma unroll
  for (int i = 0; i < 4; ++i) {
    int idx = t + i * 256;
    int row = idx >> 4, c = idx & 15;
    float2 s = st[row];
    U16x8 u;
#pragma unroll
    for (int j = 0; j < 8; ++j) {
      int col = c * 8 + j;
      float v2 = ost[row * 132 + col];
      u.s[j] = f2bf(fmaxf(fmaf((v2 - s.x) * s.y, n2_g[col], n2_b[col]), 0.f));
    }
    *(uint4*)(y3n + ((size_t)seg * 64 + row) * 128 + c * 8) = u.q;
  }
}

// ---------------- lin2: col-tiled, W in LDS, skip-add, XCD-swizzled ----------------
constexpr int NWG2 = (ROWS / 64) * 4;   // 6892
__global__ __launch_bounds__(256, 4) void k_lin2(const ushort* __restrict__ y3n,
                                                 const ushort* __restrict__ Wl2,
                                                 const float* __restrict__ lin2_b,
                                                 const float* __restrict__ x,
                                                 float* __restrict__ out) {
  __shared__ __align__(16) uint4 smem[2048];
  const int t = threadIdx.x;
  int orig = blockIdx.x;
  int xcd = orig & 7;
  int idx0 = orig >> 3;
  constexpr int q = NWG2 / 8, r = NWG2 % 8;   // 861, 4
  int wgid = (xcd < r ? xcd * (q + 1) : r * (q + 1) + (xcd - r) * q) + idx0;
  const int tile = wgid & 3;
  const int r0 = (wgid >> 2) * 64;
  const int c0 = tile * 64;
  uint4* AsQ = smem;
  uint4* WsQ = smem + 1024;

#pragma unroll
  for (int i = 0; i < 4; ++i) {
    int idx = t + i * 256;
    int row = idx >> 4, c = idx & 15;
    AsQ[row * 16 + (c ^ (row & 7))] = *(const uint4*)(y3n + (size_t)(r0 + row) * 128 + c * 8);
  }
#pragma unroll
  for (int i = 0; i < 4; ++i) {
    int idx = t + i * 256;
    int row = idx >> 4, c = idx & 15;
    WsQ[row * 16 + (c ^ (row & 7))] = *(const uint4*)(Wl2 + (size_t)(c0 + row) * 128 + c * 8);
  }
  __syncthreads();

  const int lane = t & 63;
  const int w = t >> 6;
  const int lo = lane & 15, hi = lane >> 4;
  const int wm = w & 1, wn = w >> 1;
  const int m0 = wm * 32 + lo, m1 = wm * 32 + 16 + lo;
  const bf16x8* Asv = (const bf16x8*)AsQ;
  const bf16x8* Wsv = (const bf16x8*)WsQ;
  f32x4 acc[2][2] = {};
#pragma unroll
  for (int ks = 0; ks < 4; ++ks) {
    int cb = ks * 4 + hi;
    bf16x8 a0 = Asv[m0 * 16 + (cb ^ (m0 & 7))];
    bf16x8 a1 = Asv[m1 * 16 + (cb ^ (m1 & 7))];
#pragma unroll
    for (int f = 0; f < 2; ++f) {
      int n = wn * 32 + f * 16 + lo;
      bf16x8 bfr = Wsv[n * 16 + (cb ^ (n & 7))];
      acc[0][f] = __builtin_amdgcn_mfma_f32_16x16x32_bf16(a0, bfr, acc[0][f], 0, 0, 0);
      acc[1][f] = __builtin_amdgcn_mfma_f32_16x16x32_bf16(a1, bfr, acc[1][f], 0, 0, 0);
    }
  }
  __syncthreads();

  float* ost = (float*)smem;
#pragma unroll
  for (int f = 0; f < 2; ++f) {
    int cl = wn * 32 + f * 16 + lo;
    float badd = lin2_b[c0 + cl];
#pragma unroll
    for (int i = 0; i < 2; ++i)
#pragma unroll
      for (int r2 = 0; r2 < 4; ++r2) {
        int lr = wm * 32 + i * 16 + hi * 4 + r2;
        ost[lr * 68 + cl] = acc[i][f][r2] + badd;
      }
  }
  __syncthreads();

#pragma unroll
  for (int i = 0; i < 4; ++i) {
    int idx = t + i * 256;
    int lr = idx >> 4, c4 = idx & 15;
    uint32_t rr = r0 + lr;
    uint32_t n_ = rr >> 6, b_ = rr & 63u;
    size_t obase = ((size_t)b_ * N + n_) * 256 + c0 + c4 * 4;
    float4 v = *(const float4*)&ost[lr * 68 + c4 * 4];
    float4 s = *(const float4*)(x + obase);
    v.x += s.x; v.y += s.y; v.z += s.z; v.w += s.w;
    *(float4*)(out + obase) = v;
  }
}

// ---------------- launch ----------------
extern "C" void kernel_launch(void* const* d_in, const int* in_sizes, int n_in,
                              void* d_out, int out_size, void* d_ws, size_t ws_size,
                              hipStream_t stream) {
  const float* x      = (const float*)d_in[0];
  const int*   inc    = (const int*)  d_in[1];
  const float* pre_g  = (const float*)d_in[2];
  const float* pre_b  = (const float*)d_in[3];
  const float* lin1_W = (const float*)d_in[4];
  const float* lin1_b = (const float*)d_in[5];
  const float* n1_g   = (const float*)d_in[6];
  const float* n1_b   = (const float*)d_in[7];
  const float* th1    = (const float*)d_in[8];
  const float* bi1    = (const float*)d_in[9];
  const float* th2    = (const float*)d_in[10];
  const float* bi2    = (const float*)d_in[11];
  const float* n2_g   = (const float*)d_in[12];
  const float* n2_b   = (const float*)d_in[13];
  const float* lin2_W = (const float*)d_in[14];
  const float* lin2_b = (const float*)d_in[15];
  float* out = (float*)d_out;
  char* ws = (char*)d_ws;

  int* meta = (int*)ws;
  int* cntN = meta + OFF_CNTN;
  int* cntE = meta + OFF_CNTE;
  int* nval = meta + OFF_NVAL;
  int* eval = meta + OFF_EVAL;

  ushort* Wbase = (ushort*)(ws + B_WB);
  ushort* y3n = (ushort*)(ws + B_SLOTA);   // (ROWS,128) bf16 node-major
  ushort* xl1 = (ushort*)(ws + B_SLOTB);   // (ROWS,32) bf16 node-major
  ushort* ef2 = (ushort*)(ws + B_SLOTB);   // reuse after xl1 dead
  ushort* ef1 = (ushort*)(ws + B_SLOTC);
  ushort* y2  = (ushort*)(ws + B_SLOTD);

  // CSR (bucket) build: 3 kernels
  k_init<<<CVT_BLOCKS + ZERO_BLOCKS, 256, 0, stream>>>(lin1_W, th1, th2, lin2_W, Wbase, meta);
  k_bucket<<<NNZ / 256, 256, 0, stream>>>(inc, cntN, cntE, nval, eval);
  k_sort<<<(2 * E + 255) / 256, 256, 0, stream>>>(cntN, nval, cntE, eval);

  // xl1 = th1(relu(LN(lin1(relu(LN(x))))))
  k_lin1th1<<<ROWS / 64, 256, 0, stream>>>(x, Wbase, lin1_b, pre_g, pre_b, n1_g, n1_b, xl1);

  // propagation (C=32, bf16): hconv1 then hconv2 (theta commutes with P)
  agg_bf16_k<false><<<E, 256, 0, stream>>>(xl1, cntE, eval, nullptr, ef1);
  agg_bf16_k<true ><<<E, 256, 0, stream>>>(ef1, cntN, nval, bi1, y2);
  agg_bf16_k<false><<<E, 256, 0, stream>>>(y2, cntE, eval, nullptr, ef2);

  // y3n = relu(LN(node_agg(ef2) @ th2^T + bi2))
  k_aggth2<<<E, 256, 0, stream>>>(ef2, cntN, nval, Wbase + WB_TH2, bi2, n2_g, n2_b, y3n);

  // out = x + lin2(y3n)
  k_lin2<<<NWG2, 256, 0, stream>>>(y3n, Wbase + WB_LIN2, lin2_b, x, out);
}

// Round 15
// 156.358 us; speedup vs baseline: 1.1054x; 1.0223x over previous
//
#include <hip/hip_runtime.h>
#include <cstdint>

constexpr int B  = 64;
constexpr int N  = 1723;
constexpr int E  = 1723;
constexpr int NNZ = 16384;
constexpr int ROWS = B * N;   // 110272
constexpr int CAP = 64;       // fixed per-segment bucket capacity (max degree ~30 whp)

typedef __bf16 bf16x8 __attribute__((ext_vector_type(8)));
typedef float  f32x4  __attribute__((ext_vector_type(4)));

// ---------------- workspace layout (int elements from ws base) ----------------
constexpr size_t OFF_CNTN = 0;                    // int[E]
constexpr size_t OFF_CNTE = OFF_CNTN + E;         // int[E]
constexpr size_t OFF_NVAL = OFF_CNTE + E;         // int[E*CAP]
constexpr size_t OFF_EVAL = OFF_NVAL + (size_t)E * CAP;

// bf16 weight region element offsets (within Wb)
constexpr int WB_LIN1 = 0;            // 64*256  = 16384
constexpr int WB_TH1  = 16384;        // 32*64   -> +2048
constexpr int WB_TH2  = 18432;        // 128*32  -> +4096
constexpr int WB_LIN2 = 22528;        // 256*128 -> +32768
constexpr int WB_TOT  = 55296;
constexpr int CVT_BLOCKS  = WB_TOT / 8 / 256;         // 27
constexpr int ZERO_INTS   = 2 * E;                    // 3446
constexpr int ZERO_BLOCKS = (ZERO_INTS + 255) / 256;  // 14

constexpr size_t B_WB    = 1u << 20;          // bf16 weights (110 KB)
constexpr size_t B_SLOTA = 2u << 20;          // y3n bf16 (ROWS,128) = 28.2 MB
constexpr size_t B_SLOTB = B_SLOTA + (30u << 20);  // xl1 / ef2 (7.06 MB)
constexpr size_t B_SLOTC = B_SLOTB + (8u << 20);   // ef1
constexpr size_t B_SLOTD = B_SLOTC + (8u << 20);   // y2

// ---------------- helpers ----------------
__device__ __forceinline__ ushort f2bf(float f) {
  uint32_t b = __float_as_uint(f);
  b += 0x7fffu + ((b >> 16) & 1u);
  return (ushort)(b >> 16);
}
__device__ __forceinline__ float bf2f(ushort u) {
  return __uint_as_float((uint32_t)u << 16);
}
union U16x8 { uint4 q; ushort s[8]; };

// ---------------- init: weights -> bf16 AND zero bucket counters ----------------
__global__ __launch_bounds__(256) void k_init(const float* __restrict__ W1, const float* __restrict__ W2,
                                              const float* __restrict__ W3, const float* __restrict__ W4,
                                              ushort* __restrict__ out, int* __restrict__ zr) {
  int bid = blockIdx.x;
  if (bid < CVT_BLOCKS) {
    int e = (bid * 256 + threadIdx.x) * 8;
    const float* src;
    int off;
    if (e < WB_TH1)      { src = W1; off = e - WB_LIN1; }
    else if (e < WB_TH2) { src = W2; off = e - WB_TH1; }
    else if (e < WB_LIN2){ src = W3; off = e - WB_TH2; }
    else                 { src = W4; off = e - WB_LIN2; }
    float4 v0 = *(const float4*)(src + off);
    float4 v1 = *(const float4*)(src + off + 4);
    U16x8 u;
    u.s[0] = f2bf(v0.x); u.s[1] = f2bf(v0.y); u.s[2] = f2bf(v0.z); u.s[3] = f2bf(v0.w);
    u.s[4] = f2bf(v1.x); u.s[5] = f2bf(v1.y); u.s[6] = f2bf(v1.z); u.s[7] = f2bf(v1.w);
    *(uint4*)(out + e) = u.q;
  } else {
    int i = (bid - CVT_BLOCKS) * 256 + threadIdx.x;
    if (i < ZERO_INTS) zr[i] = 0;
  }
}

// ---------------- bucket fill: fixed stride CAP, no offsets needed ----------------
__global__ __launch_bounds__(256) void k_bucket(const int* __restrict__ inc,
                                                int* __restrict__ cntN, int* __restrict__ cntE,
                                                int* __restrict__ nval, int* __restrict__ eval) {
  int k = blockIdx.x * 256 + threadIdx.x;
  int n = inc[k], e = inc[NNZ + k];
  int p = atomicAdd(&cntE[e], 1);
  if (p < CAP) eval[e * CAP + p] = n;
  int q = atomicAdd(&cntN[n], 1);
  if (q < CAP) nval[n * CAP + q] = e;
}

// per-segment insertion sort in LDS scratch (stride 33 -> conflict-free); deterministic order
__global__ __launch_bounds__(256) void k_sort(const int* __restrict__ cntN, int* __restrict__ nval,
                                              const int* __restrict__ cntE, int* __restrict__ eval) {
  __shared__ int buf[256][33];
  int s = blockIdx.x * 256 + threadIdx.x;
  const int* cnt;
  int* vals;
  if (s < E) { cnt = cntN; vals = nval; }
  else if (s < 2 * E) { cnt = cntE; vals = eval; s -= E; }
  else return;
  int len = cnt[s];
  if (len > CAP) len = CAP;
  int base = s * CAP;
  int* loc = buf[threadIdx.x];
  if (len <= 32) {
    for (int i = 0; i < len; ++i) loc[i] = vals[base + i];
    for (int i = 1; i < len; ++i) {
      int v = loc[i];
      int j = i - 1;
      while (j >= 0 && loc[j] > v) { loc[j + 1] = loc[j]; --j; }
      loc[j + 1] = v;
    }
    for (int i = 0; i < len; ++i) vals[base + i] = loc[i];
  } else {
    for (int i = 1; i < len; ++i) {
      int v = vals[base + i];
      int j = i - 1;
      while (j >= 0 && vals[base + j] > v) { vals[base + j + 1] = vals[base + j]; --j; }
      vals[base + j + 1] = v;
    }
  }
}

// ---------------- fused lin1 + LN + relu + th1 ----------------
__global__ __launch_bounds__(256, 3) void k_lin1th1(const float* __restrict__ x,
                                                    const ushort* __restrict__ Wb,
                                                    const float* __restrict__ lin1_b,
                                                    const float* __restrict__ pre_g,
                                                    const float* __restrict__ pre_b,
                                                    const float* __restrict__ n1_g,
                                                    const float* __restrict__ n1_b,
                                                    ushort* __restrict__ xl1) {
  __shared__ __align__(16) uint4 R0[2048];   // A1 [64][32]; later: ost f32[64][68] @0, A2 @1152
  __shared__ __align__(16) uint4 W2s[256];   // th1 [32][8]
  __shared__ float2 st[64];

  const int t = threadIdx.x;
  const int r0 = blockIdx.x * 64;
  const ushort* W1 = Wb + WB_LIN1;
  const ushort* W2 = Wb + WB_TH1;

  const int lane = t & 63;
  const int w = t >> 6;
  const int lo = lane & 15, hi = lane >> 4;
  const int wm = w & 1, wn = w >> 1;
  const int m0 = wm * 32 + lo, m1 = wm * 32 + 16 + lo;

  // lin1 W fragments -> registers (L2-resident 32KB)
  bf16x8 wf[16];
#pragma unroll
  for (int ks = 0; ks < 8; ++ks)
#pragma unroll
    for (int f = 0; f < 2; ++f) {
      int n = wn * 32 + f * 16 + lo;
      wf[ks * 2 + f] = *(const bf16x8*)(W1 + (size_t)n * 256 + (ks * 4 + hi) * 8);
    }

  {
    int row = t >> 3, c = t & 7;
    W2s[row * 8 + (c ^ (row & 7))] = *(const uint4*)(W2 + row * 64 + c * 8);
  }
#pragma unroll
  for (int i = 0; i < 8; ++i) {
    int idx = t + i * 256;
    int row = idx >> 5, c = idx & 31;
    const float* src = x + (size_t)(r0 + row) * 256 + c * 8;
    float4 v0 = *(const float4*)src;
    float4 v1 = *(const float4*)(src + 4);
    U16x8 u;
    u.s[0] = f2bf(v0.x); u.s[1] = f2bf(v0.y); u.s[2] = f2bf(v0.z); u.s[3] = f2bf(v0.w);
    u.s[4] = f2bf(v1.x); u.s[5] = f2bf(v1.y); u.s[6] = f2bf(v1.z); u.s[7] = f2bf(v1.w);
    R0[row * 32 + (c ^ (row & 7))] = u.q;
  }
  __syncthreads();

  // LN1 stats
  {
    int row = t >> 2, part = t & 3;
    float s1 = 0.f, s2 = 0.f;
#pragma unroll
    for (int i = 0; i < 8; ++i) {
      int c = part * 8 + i;
      U16x8 u; u.q = R0[row * 32 + (c ^ (row & 7))];
#pragma unroll
      for (int j = 0; j < 8; ++j) { float v = bf2f(u.s[j]); s1 += v; s2 += v * v; }
    }
    s1 += __shfl_xor(s1, 1, 64); s2 += __shfl_xor(s2, 1, 64);
    s1 += __shfl_xor(s1, 2, 64); s2 += __shfl_xor(s2, 2, 64);
    if (part == 0) {
      float mu = s1 / 256.f;
      float var = fmaxf(s2 / 256.f - mu * mu, 0.f);
      st[row] = make_float2(mu, rsqrtf(var + 1e-5f));
    }
  }
  __syncthreads();
  // apply LN1 + relu in place
#pragma unroll
  for (int i = 0; i < 8; ++i) {
    int idx = t + i * 256;
    int row = idx >> 5, c = idx & 31;
    int slot = row * 32 + (c ^ (row & 7));
    U16x8 u; u.q = R0[slot];
    float2 s = st[row];
    float4 g0 = *(const float4*)(pre_g + c * 8);
    float4 g1 = *(const float4*)(pre_g + c * 8 + 4);
    float4 b0 = *(const float4*)(pre_b + c * 8);
    float4 b1 = *(const float4*)(pre_b + c * 8 + 4);
    U16x8 o;
    o.s[0] = f2bf(fmaxf(fmaf((bf2f(u.s[0]) - s.x) * s.y, g0.x, b0.x), 0.f));
    o.s[1] = f2bf(fmaxf(fmaf((bf2f(u.s[1]) - s.x) * s.y, g0.y, b0.y), 0.f));
    o.s[2] = f2bf(fmaxf(fmaf((bf2f(u.s[2]) - s.x) * s.y, g0.z, b0.z), 0.f));
    o.s[3] = f2bf(fmaxf(fmaf((bf2f(u.s[3]) - s.x) * s.y, g0.w, b0.w), 0.f));
    o.s[4] = f2bf(fmaxf(fmaf((bf2f(u.s[4]) - s.x) * s.y, g1.x, b1.x), 0.f));
    o.s[5] = f2bf(fmaxf(fmaf((bf2f(u.s[5]) - s.x) * s.y, g1.y, b1.y), 0.f));
    o.s[6] = f2bf(fmaxf(fmaf((bf2f(u.s[6]) - s.x) * s.y, g1.z, b1.z), 0.f));
    o.s[7] = f2bf(fmaxf(fmaf((bf2f(u.s[7]) - s.x) * s.y, g1.w, b1.w), 0.f));
    R0[slot] = o.q;
  }
  __syncthreads();

  // MFMA1: K=256, NOUT=64; B-frags from registers
  const bf16x8* Asv = (const bf16x8*)R0;
  f32x4 acc1[2][2] = {};
#pragma unroll
  for (int ks = 0; ks < 8; ++ks) {
    int cb = ks * 4 + hi;
    bf16x8 a0 = Asv[m0 * 32 + (cb ^ (m0 & 7))];
    bf16x8 a1 = Asv[m1 * 32 + (cb ^ (m1 & 7))];
#pragma unroll
    for (int f = 0; f < 2; ++f) {
      acc1[0][f] = __builtin_amdgcn_mfma_f32_16x16x32_bf16(a0, wf[ks * 2 + f], acc1[0][f], 0, 0, 0);
      acc1[1][f] = __builtin_amdgcn_mfma_f32_16x16x32_bf16(a1, wf[ks * 2 + f], acc1[1][f], 0, 0, 0);
    }
  }
  __syncthreads();

  float* ost = (float*)R0;
#pragma unroll
  for (int f = 0; f < 2; ++f) {
    int colg = wn * 32 + f * 16 + lo;
    float badd = lin1_b[colg];
#pragma unroll
    for (int i = 0; i < 2; ++i)
#pragma unroll
      for (int r = 0; r < 4; ++r) {
        int lr = wm * 32 + i * 16 + hi * 4 + r;
        ost[lr * 68 + colg] = acc1[i][f][r] + badd;
      }
  }
  __syncthreads();

  // LN2 stats
  {
    int row = t >> 2, part = t & 3;
    float s1 = 0.f, s2 = 0.f;
#pragma unroll
    for (int i = 0; i < 16; ++i) {
      float v = ost[row * 68 + part * 16 + i];
      s1 += v; s2 += v * v;
    }
    s1 += __shfl_xor(s1, 1, 64); s2 += __shfl_xor(s2, 1, 64);
    s1 += __shfl_xor(s1, 2, 64); s2 += __shfl_xor(s2, 2, 64);
    if (part == 0) {
      float mu = s1 / 64.f;
      float var = fmaxf(s2 / 64.f - mu * mu, 0.f);
      st[row] = make_float2(mu, rsqrtf(var + 1e-5f));
    }
  }
  __syncthreads();
  uint4* A2q = R0 + 1152;
#pragma unroll
  for (int i = 0; i < 2; ++i) {
    int idx = t + i * 256;
    int row = idx >> 3, c = idx & 7;
    float2 s = st[row];
    U16x8 u;
#pragma unroll
    for (int j = 0; j < 8; ++j) {
      int col = c * 8 + j;
      float v = ost[row * 68 + col];
      u.s[j] = f2bf(fmaxf(fmaf((v - s.x) * s.y, n1_g[col], n1_b[col]), 0.f));
    }
    A2q[row * 8 + (c ^ (row & 7))] = u.q;
  }
  __syncthreads();

  // MFMA2: K=64, NOUT=32
  const bf16x8* A2v = (const bf16x8*)A2q;
  f32x4 acc2[2] = {};
#pragma unroll
  for (int ks = 0; ks < 2; ++ks) {
    int cb = ks * 4 + hi;
    bf16x8 a0 = A2v[m0 * 8 + (cb ^ (m0 & 7))];
    bf16x8 a1 = A2v[m1 * 8 + (cb ^ (m1 & 7))];
    int n = wn * 16 + lo;
    bf16x8 bfr = ((const bf16x8*)W2s)[n * 8 + (cb ^ (n & 7))];
    acc2[0] = __builtin_amdgcn_mfma_f32_16x16x32_bf16(a0, bfr, acc2[0], 0, 0, 0);
    acc2[1] = __builtin_amdgcn_mfma_f32_16x16x32_bf16(a1, bfr, acc2[1], 0, 0, 0);
  }
  {
    int colg = wn * 16 + lo;
#pragma unroll
    for (int i = 0; i < 2; ++i)
#pragma unroll
      for (int r = 0; r < 4; ++r) {
        int lr = wm * 32 + i * 16 + hi * 4 + r;
        ost[lr * 36 + colg] = acc2[i][r];
      }
  }
  __syncthreads();
  {
    int lr = t >> 2, c8 = t & 3;
    uint32_t r = r0 + lr;
    uint32_t b_ = r / (uint32_t)N;
    uint32_t n_ = r - b_ * (uint32_t)N;
    U16x8 u;
#pragma unroll
    for (int j = 0; j < 8; ++j) u.s[j] = f2bf(ost[lr * 36 + c8 * 8 + j]);
    *(uint4*)(xl1 + ((size_t)n_ * 64 + b_) * 32 + c8 * 8) = u.q;
  }
}

// ---------------- bf16 hypergraph aggregation, C=32, bucket CSR, 2-deep pipelined ------------
template <bool HASB>
__global__ __launch_bounds__(256) void agg_bf16_k(const ushort* __restrict__ in,
                                                  const int* __restrict__ cnt,
                                                  const int* __restrict__ vals,
                                                  const float* __restrict__ bias,
                                                  ushort* __restrict__ outb) {
  const int seg = blockIdx.x;
  int len = cnt[seg];
  if (len > CAP) len = CAP;
  const int* v = vals + seg * CAP;
  const int t = threadIdx.x;
  float acc[8] = {0.f, 0.f, 0.f, 0.f, 0.f, 0.f, 0.f, 0.f};
  if (len > 0) {
    uint4 cur = *(const uint4*)(in + (size_t)v[0] * 2048 + t * 8);
    for (int k = 1; k < len; ++k) {
      uint4 nxt = *(const uint4*)(in + (size_t)v[k] * 2048 + t * 8);
      U16x8 u; u.q = cur;
#pragma unroll
      for (int j = 0; j < 8; ++j) acc[j] += bf2f(u.s[j]);
      cur = nxt;
    }
    U16x8 u; u.q = cur;
#pragma unroll
    for (int j = 0; j < 8; ++j) acc[j] += bf2f(u.s[j]);
  }
  float inv = (len > 0) ? 1.f / (float)len : 0.f;
  U16x8 o;
  if constexpr (HASB) {
    int cb = (t & 3) * 8;
#pragma unroll
    for (int j = 0; j < 8; ++j) o.s[j] = f2bf(acc[j] * inv + bias[cb + j]);
  } else {
#pragma unroll
    for (int j = 0; j < 8; ++j) o.s[j] = f2bf(acc[j] * inv);
  }
  *(uint4*)(outb + (size_t)seg * 2048 + t * 8) = o.q;
}

// ---------------- fused node-agg + th2 + bi2 + LN + relu ----------------
__global__ __launch_bounds__(256, 3) void k_aggth2(const ushort* __restrict__ ef2,
                                                   const int* __restrict__ cntN,
                                                   const int* __restrict__ nval,
                                                   const ushort* __restrict__ W2b,
                                                   const float* __restrict__ bi2,
                                                   const float* __restrict__ n2_g,
                                                   const float* __restrict__ n2_b,
                                                   ushort* __restrict__ y3n) {
  __shared__ __align__(16) uint4 A2s[256];   // [64][4]
  __shared__ __align__(16) uint4 W2s[512];   // [128][4]
  __shared__ float ost[64 * 132];
  __shared__ float2 st[64];
  const int t = threadIdx.x;
  const int seg = blockIdx.x;

#pragma unroll
  for (int i = 0; i < 2; ++i) {
    int idx = t + i * 256;
    int row = idx >> 2, c = idx & 3;
    W2s[row * 4 + (c ^ (row & 3))] = *(const uint4*)(W2b + row * 32 + c * 8);
  }
  // gather (bucket CSR, 2-deep pipelined)
  int len = cntN[seg];
  if (len > CAP) len = CAP;
  const int* v = nval + seg * CAP;
  float acc[8] = {0.f, 0.f, 0.f, 0.f, 0.f, 0.f, 0.f, 0.f};
  if (len > 0) {
    uint4 cur = *(const uint4*)(ef2 + (size_t)v[0] * 2048 + t * 8);
    for (int k = 1; k < len; ++k) {
      uint4 nxt = *(const uint4*)(ef2 + (size_t)v[k] * 2048 + t * 8);
      U16x8 u; u.q = cur;
#pragma unroll
      for (int j = 0; j < 8; ++j) acc[j] += bf2f(u.s[j]);
      cur = nxt;
    }
    U16x8 u; u.q = cur;
#pragma unroll
    for (int j = 0; j < 8; ++j) acc[j] += bf2f(u.s[j]);
  }
  float inv = (len > 0) ? 1.f / (float)len : 0.f;
  {
    U16x8 u;
#pragma unroll
    for (int j = 0; j < 8; ++j) u.s[j] = f2bf(acc[j] * inv);
    int row = t >> 2, c = t & 3;
    A2s[row * 4 + (c ^ (row & 3))] = u.q;
  }
  __syncthreads();

  // MFMA: K=32 (1 step), NOUT=128
  const int lane = t & 63;
  const int w = t >> 6;
  const int lo = lane & 15, hi = lane >> 4;
  const int wm = w & 1, wn = w >> 1;
  const int m0 = wm * 32 + lo, m1 = wm * 32 + 16 + lo;
  const bf16x8* Asv = (const bf16x8*)A2s;
  const bf16x8* Wsv = (const bf16x8*)W2s;
  f32x4 acc2[2][4] = {};
  {
    bf16x8 a0 = Asv[m0 * 4 + (hi ^ (m0 & 3))];
    bf16x8 a1 = Asv[m1 * 4 + (hi ^ (m1 & 3))];
#pragma unroll
    for (int f = 0; f < 4; ++f) {
      int n = wn * 64 + f * 16 + lo;
      bf16x8 bfr = Wsv[n * 4 + (hi ^ (n & 3))];
      acc2[0][f] = __builtin_amdgcn_mfma_f32_16x16x32_bf16(a0, bfr, acc2[0][f], 0, 0, 0);
      acc2[1][f] = __builtin_amdgcn_mfma_f32_16x16x32_bf16(a1, bfr, acc2[1][f], 0, 0, 0);
    }
  }
#pragma unroll
  for (int f = 0; f < 4; ++f) {
    int colg = wn * 64 + f * 16 + lo;
    float badd = bi2[colg];
#pragma unroll
    for (int i = 0; i < 2; ++i)
#pragma unroll
      for (int r = 0; r < 4; ++r) {
        int lr = wm * 32 + i * 16 + hi * 4 + r;
        ost[lr * 132 + colg] = acc2[i][f][r] + badd;
      }
  }
  __syncthreads();
  // LN stats over 128
  {
    int row = t >> 2, part = t & 3;
    float s1 = 0.f, s2 = 0.f;
#pragma unroll
    for (int i = 0; i < 32; ++i) {
      float v2 = ost[row * 132 + part * 32 + i];
      s1 += v2; s2 += v2 * v2;
    }
    s1 += __shfl_xor(s1, 1, 64); s2 += __shfl_xor(s2, 1, 64);
    s1 += __shfl_xor(s1, 2, 64); s2 += __shfl_xor(s2, 2, 64);
    if (part == 0) {
      float mu = s1 / 128.f;
      float var = fmaxf(s2 / 128.f - mu * mu, 0.f);
      st[row] = make_float2(mu, rsqrtf(var + 1e-5f));
    }
  }
  __syncthreads();
#pragma unroll
  for (int i = 0; i < 4; ++i) {
    int idx = t + i * 256;
    int row = idx >> 4, c = idx & 15;
    float2 s = st[row];
    U16x8 u;
#pragma unroll
    for (int j = 0; j < 8; ++j) {
      int col = c * 8 + j;
      float v2 = ost[row * 132 + col];
      u.s[j] = f2bf(fmaxf(fmaf((v2 - s.x) * s.y, n2_g[col], n2_b[col]), 0.f));
    }
    *(uint4*)(y3n + ((size_t)seg * 64 + row) * 128 + c * 8) = u.q;
  }
}

// ---------------- lin2: batch-major row blocks (contiguous x/out streams), y3n gathered ------
constexpr int NWG2 = (ROWS / 64) * 4;   // 6892
__global__ __launch_bounds__(256, 4) void k_lin2(const ushort* __restrict__ y3n,
                                                 const ushort* __restrict__ Wl2,
                                                 const float* __restrict__ lin2_b,
                                                 const float* __restrict__ x,
                                                 float* __restrict__ out) {
  __shared__ __align__(16) uint4 smem[2048];  // A [64][16] + W [64][16]; ost overlay [64][68] f32
  const int t = threadIdx.x;
  // bijective XCD swizzle (m204); wgid tile-fastest so 4 tiles of one row-block share an XCD
  int orig = blockIdx.x;
  int xcd = orig & 7;
  int idx0 = orig >> 3;
  constexpr int q = NWG2 / 8, r = NWG2 % 8;   // 861, 4
  int wgid = (xcd < r ? xcd * (q + 1) : r * (q + 1) + (xcd - r) * q) + idx0;
  const int tile = wgid & 3;
  const int r0 = (wgid >> 2) * 64;            // batch-major row base (r = b*N + n)
  const int c0 = tile * 64;
  uint4* AsQ = smem;
  uint4* WsQ = smem + 1024;

  // stage A: y3n rows gathered via node-major remap (small L3-resident buffer)
#pragma unroll
  for (int i = 0; i < 4; ++i) {
    int idx = t + i * 256;
    int row = idx >> 4, c = idx & 15;
    uint32_t rr = r0 + row;
    uint32_t b_ = rr / (uint32_t)N;
    uint32_t n_ = rr - b_ * (uint32_t)N;
    AsQ[row * 16 + (c ^ (row & 7))] = *(const uint4*)(y3n + ((size_t)n_ * 64 + b_) * 128 + c * 8);
  }
#pragma unroll
  for (int i = 0; i < 4; ++i) {
    int idx = t + i * 256;
    int row = idx >> 4, c = idx & 15;
    WsQ[row * 16 + (c ^ (row & 7))] = *(const uint4*)(Wl2 + (size_t)(c0 + row) * 128 + c * 8);
  }
  __syncthreads();

  const int lane = t & 63;
  const int w = t >> 6;
  const int lo = lane & 15, hi = lane >> 4;
  const int wm = w & 1, wn = w >> 1;
  const int m0 = wm * 32 + lo, m1 = wm * 32 + 16 + lo;
  const bf16x8* Asv = (const bf16x8*)AsQ;
  const bf16x8* Wsv = (const bf16x8*)WsQ;
  f32x4 acc[2][2] = {};
#pragma unroll
  for (int ks = 0; ks < 4; ++ks) {
    int cb = ks * 4 + hi;
    bf16x8 a0 = Asv[m0 * 16 + (cb ^ (m0 & 7))];
    bf16x8 a1 = Asv[m1 * 16 + (cb ^ (m1 & 7))];
#pragma unroll
    for (int f = 0; f < 2; ++f) {
      int n = wn * 32 + f * 16 + lo;
      bf16x8 bfr = Wsv[n * 16 + (cb ^ (n & 7))];
      acc[0][f] = __builtin_amdgcn_mfma_f32_16x16x32_bf16(a0, bfr, acc[0][f], 0, 0, 0);
      acc[1][f] = __builtin_amdgcn_mfma_f32_16x16x32_bf16(a1, bfr, acc[1][f], 0, 0, 0);
    }
  }
  __syncthreads();

  float* ost = (float*)smem;
#pragma unroll
  for (int f = 0; f < 2; ++f) {
    int cl = wn * 32 + f * 16 + lo;
    float badd = lin2_b[c0 + cl];
#pragma unroll
    for (int i = 0; i < 2; ++i)
#pragma unroll
      for (int r2 = 0; r2 < 4; ++r2) {
        int lr = wm * 32 + i * 16 + hi * 4 + r2;
        ost[lr * 68 + cl] = acc[i][f][r2] + badd;
      }
  }
  __syncthreads();

  // skip + write: batch-major rows -> fully contiguous x/out streams
#pragma unroll
  for (int i = 0; i < 4; ++i) {
    int idx = t + i * 256;
    int lr = idx >> 4, c4 = idx & 15;
    size_t obase = ((size_t)(r0 + lr)) * 256 + c0 + c4 * 4;
    float4 v = *(const float4*)&ost[lr * 68 + c4 * 4];
    float4 s = *(const float4*)(x + obase);
    v.x += s.x; v.y += s.y; v.z += s.z; v.w += s.w;
    *(float4*)(out + obase) = v;
  }
}

// ---------------- launch ----------------
extern "C" void kernel_launch(void* const* d_in, const int* in_sizes, int n_in,
                              void* d_out, int out_size, void* d_ws, size_t ws_size,
                              hipStream_t stream) {
  const float* x      = (const float*)d_in[0];
  const int*   inc    = (const int*)  d_in[1];
  const float* pre_g  = (const float*)d_in[2];
  const float* pre_b  = (const float*)d_in[3];
  const float* lin1_W = (const float*)d_in[4];
  const float* lin1_b = (const float*)d_in[5];
  const float* n1_g   = (const float*)d_in[6];
  const float* n1_b   = (const float*)d_in[7];
  const float* th1    = (const float*)d_in[8];
  const float* bi1    = (const float*)d_in[9];
  const float* th2    = (const float*)d_in[10];
  const float* bi2    = (const float*)d_in[11];
  const float* n2_g   = (const float*)d_in[12];
  const float* n2_b   = (const float*)d_in[13];
  const float* lin2_W = (const float*)d_in[14];
  const float* lin2_b = (const float*)d_in[15];
  float* out = (float*)d_out;
  char* ws = (char*)d_ws;

  int* meta = (int*)ws;
  int* cntN = meta + OFF_CNTN;
  int* cntE = meta + OFF_CNTE;
  int* nval = meta + OFF_NVAL;
  int* eval = meta + OFF_EVAL;

  ushort* Wbase = (ushort*)(ws + B_WB);
  ushort* y3n = (ushort*)(ws + B_SLOTA);   // (ROWS,128) bf16 node-major
  ushort* xl1 = (ushort*)(ws + B_SLOTB);   // (ROWS,32) bf16 node-major
  ushort* ef2 = (ushort*)(ws + B_SLOTB);   // reuse after xl1 dead
  ushort* ef1 = (ushort*)(ws + B_SLOTC);
  ushort* y2  = (ushort*)(ws + B_SLOTD);

  // CSR (bucket) build: 3 kernels
  k_init<<<CVT_BLOCKS + ZERO_BLOCKS, 256, 0, stream>>>(lin1_W, th1, th2, lin2_W, Wbase, meta);
  k_bucket<<<NNZ / 256, 256, 0, stream>>>(inc, cntN, cntE, nval, eval);
  k_sort<<<(2 * E + 255) / 256, 256, 0, stream>>>(cntN, nval, cntE, eval);

  // xl1 = th1(relu(LN(lin1(relu(LN(x))))))
  k_lin1th1<<<ROWS / 64, 256, 0, stream>>>(x, Wbase, lin1_b, pre_g, pre_b, n1_g, n1_b, xl1);

  // propagation (C=32, bf16): hconv1 then hconv2 (theta commutes with P)
  agg_bf16_k<false><<<E, 256, 0, stream>>>(xl1, cntE, eval, nullptr, ef1);
  agg_bf16_k<true ><<<E, 256, 0, stream>>>(ef1, cntN, nval, bi1, y2);
  agg_bf16_k<false><<<E, 256, 0, stream>>>(y2, cntE, eval, nullptr, ef2);

  // y3n = relu(LN(node_agg(ef2) @ th2^T + bi2))
  k_aggth2<<<E, 256, 0, stream>>>(ef2, cntN, nval, Wbase + WB_TH2, bi2, n2_g, n2_b, y3n);

  // out = x + lin2(y3n)
  k_lin2<<<NWG2, 256, 0, stream>>>(y3n, Wbase + WB_LIN2, lin2_b, x, out);
}